// Round 13
// baseline (1272.926 us; speedup 1.0000x reference)
//
#include <hip/hip_runtime.h>
#include <stdint.h>

typedef __attribute__((ext_vector_type(4))) float f32x4;
typedef __attribute__((ext_vector_type(8))) short bf16x8;

#define HIDC 256
#define MSGC 128
#define NLAYER 10

__device__ __forceinline__ ushort f2bf(float f) {
  union { float f; uint32_t u; } a; a.f = f;
  uint32_t u = a.u;
  return (ushort)((u + 0x7fffu + ((u >> 16) & 1u)) >> 16);
}
__device__ __forceinline__ float bf2f(ushort h) {
  union { float f; uint32_t u; } a; a.u = ((uint32_t)h) << 16;
  return a.f;
}

// async global->LDS, 16B per lane; dst is wave-uniform base (lane*16 added by HW)
__device__ __forceinline__ void gll16(const void* g, void* l) {
  __builtin_amdgcn_global_load_lds(
      (const __attribute__((address_space(1))) void*)g,
      (__attribute__((address_space(3))) void*)l, 16, 0, 0);
}

// ---------------------------------------------------------------------------
// W1 GEMM: A bf16 [M x 256], B bf16 [128 x 256](T), C bf16 [M x 128].
// Tile 64x128, 4 waves, BK=64, RELU fused. (known-good single-buffer)
// ---------------------------------------------------------------------------
__global__ __launch_bounds__(256, 4) void gemm_w1_64(
    const ushort* __restrict__ A, const ushort* __restrict__ B,
    const float* __restrict__ bias, ushort* __restrict__ C, int M) {
  __shared__ ushort lA[64 * 64];
  __shared__ ushort lB[128 * 64];
  const int tid = threadIdx.x;
  const int m0 = blockIdx.x * 64;
  const int lane = tid & 63;
  const int w = tid >> 6;
  const int wm = (w >> 1) * 32;  // 0,32
  const int wn = (w & 1) * 64;   // 0,64
  const int rr = tid >> 3;       // 0..31
  const int cc = tid & 7;        // 0..7
  const int ccs = cc ^ (rr & 7);
  const bool full = (m0 + 64 <= M);
  f32x4 acc[2][4] = {};

#pragma unroll
  for (int s = 0; s < 4; ++s) {  // K = 256
    const int k0 = s * 64;
    if (full) {
#pragma unroll
      for (int p = 0; p < 2; ++p) {
        const int row = p * 32 + rr;
        gll16(A + (size_t)(m0 + row) * 256 + k0 + ccs * 8,
              lA + (size_t)(p * 32 + w * 8) * 64);
      }
    } else {
#pragma unroll
      for (int p = 0; p < 2; ++p) {
        const int row = p * 32 + rr;
        const int gm = m0 + row;
        bf16x8 av = {0, 0, 0, 0, 0, 0, 0, 0};
        if (gm < M) av = *(const bf16x8*)(A + (size_t)gm * 256 + k0 + cc * 8);
        const uint32_t off = (uint32_t)((row * 128 + cc * 16) ^ ((row & 7) << 4));
        *(bf16x8*)((char*)lA + off) = av;
      }
    }
#pragma unroll
    for (int p = 0; p < 4; ++p) {
      const int row = p * 32 + rr;
      gll16(B + (size_t)row * 256 + k0 + ccs * 8,
            lB + (size_t)(p * 32 + w * 8) * 64);
    }
    __syncthreads();
#pragma unroll
    for (int kk = 0; kk < 2; ++kk) {
      bf16x8 ah[2];
#pragma unroll
      for (int i = 0; i < 2; ++i) {
        const int arow = wm + i * 16 + (lane & 15);
        const uint32_t ao =
            (uint32_t)((arow * 128 + kk * 64 + ((lane >> 4) * 16)) ^ ((arow & 7) << 4));
        ah[i] = *(const bf16x8*)((const char*)lA + ao);
      }
#pragma unroll
      for (int j = 0; j < 4; ++j) {
        const int brow = wn + j * 16 + (lane & 15);
        const uint32_t bo =
            (uint32_t)((brow * 128 + kk * 64 + ((lane >> 4) * 16)) ^ ((brow & 7) << 4));
        const bf16x8 bv = *(const bf16x8*)((const char*)lB + bo);
#pragma unroll
        for (int i = 0; i < 2; ++i)
          acc[i][j] = __builtin_amdgcn_mfma_f32_16x16x32_bf16(ah[i], bv, acc[i][j], 0, 0, 0);
      }
    }
    __syncthreads();
  }
  float bi[4];
#pragma unroll
  for (int j = 0; j < 4; ++j) bi[j] = bias[wn + j * 16 + (lane & 15)];
#pragma unroll
  for (int i = 0; i < 2; ++i) {
    const int gm0 = m0 + wm + i * 16 + ((lane >> 4) << 2);
#pragma unroll
    for (int r = 0; r < 4; ++r) {
      const int gm = gm0 + r;
      if (gm < M) {
        const size_t base = (size_t)gm * 128 + wn + (lane & 15);
#pragma unroll
        for (int j = 0; j < 4; ++j)
          C[base + j * 16] = f2bf(fmaxf(acc[i][j][r] + bi[j], 0.f));
      }
    }
  }
}

// ---------------------------------------------------------------------------
// Big GEMM 64-row, double-buffered: A bf16 [M x K], B bf16 [256 x K],
// tile 64x256, 4 waves, BK=32, 2-phase prefetch (stage next ∥ compute cur).
// LDS 2x(4+16)+2 = 42 KB -> 3 blocks/CU.
// LN=0: C = bf16(act(A@B^T + bias [+Z]));  LN=1: C = bf16(LN(..)*g+b_)
// ---------------------------------------------------------------------------
template <int RELU, int ADDZ, int LN>
__global__ __launch_bounds__(256, 3) void gemm_big64(
    const ushort* __restrict__ A, const ushort* __restrict__ B,
    const float* __restrict__ bias, const ushort* __restrict__ Z,
    ushort* __restrict__ C, const float* __restrict__ g,
    const float* __restrict__ b_, int M, int K) {
  __shared__ ushort lA[2][64 * 32];
  __shared__ ushort lB[2][256 * 32];
  __shared__ float sstat[2][4][64];
  const int tid = threadIdx.x;
  const int m0 = blockIdx.x * 64;
  const int lane = tid & 63;
  const int w = tid >> 6;    // 0..3
  const int wn = w * 64;     // col slice per wave
  const int srow = tid >> 2; // 0..63 (stage row)
  const int scc = tid & 3;   // 16B chunk within 64B row
  const bool full = (m0 + 64 <= M);
  f32x4 acc[4][4] = {};
  const int nsteps = K >> 5;

  auto stage = [&](int s, int buf) {
    const int k0 = s * 32;
    // A: 64 rows x 32 bf16 (one pass)
    if (full) {
      const int ccs = scc ^ ((srow >> 1) & 3);
      gll16(A + (size_t)(m0 + srow) * K + k0 + ccs * 8, &lA[buf][(w * 16) * 32]);
    } else {
      const int gm = m0 + srow;
      bf16x8 av = {0, 0, 0, 0, 0, 0, 0, 0};
      if (gm < M) av = *(const bf16x8*)(A + (size_t)gm * K + k0 + scc * 8);
      const uint32_t off = (uint32_t)((srow * 64 + scc * 16) ^ ((srow & 6) << 3));
      *(bf16x8*)((char*)lA[buf] + off) = av;
    }
    // B: 256 rows x 32, 4 passes
#pragma unroll
    for (int p = 0; p < 4; ++p) {
      const int row = p * 64 + srow;
      const int ccs = scc ^ ((row >> 1) & 3);
      gll16(B + (size_t)row * K + k0 + ccs * 8, &lB[buf][(p * 64 + w * 16) * 32]);
    }
  };

  int cur = 0;
  stage(0, 0);
  for (int s = 0; s < nsteps; ++s) {
    __syncthreads();  // buf[cur] staged; all reads of buf[cur^1] done
    if (s + 1 < nsteps) stage(s + 1, cur ^ 1);  // fly during compute
    bf16x8 ah[4];
#pragma unroll
    for (int i = 0; i < 4; ++i) {
      const int arow = i * 16 + (lane & 15);
      const uint32_t ao =
          (uint32_t)((arow * 64 + ((lane >> 4) * 16)) ^ ((arow & 6) << 3));
      ah[i] = *(const bf16x8*)((const char*)lA[cur] + ao);
    }
#pragma unroll
    for (int j = 0; j < 4; ++j) {
      const int brow = wn + j * 16 + (lane & 15);
      const uint32_t bo =
          (uint32_t)((brow * 64 + ((lane >> 4) * 16)) ^ ((brow & 6) << 3));
      const bf16x8 bv = *(const bf16x8*)((const char*)lB[cur] + bo);
#pragma unroll
      for (int i = 0; i < 4; ++i)
        acc[i][j] = __builtin_amdgcn_mfma_f32_16x16x32_bf16(ah[i], bv, acc[i][j], 0, 0, 0);
    }
    cur ^= 1;
  }
  __syncthreads();

  float bi[4];
#pragma unroll
  for (int j = 0; j < 4; ++j) bi[j] = bias[wn + j * 16 + (lane & 15)];

  if (LN) {
    float gv[4], bv[4];
#pragma unroll
    for (int j = 0; j < 4; ++j) {
      gv[j] = g[wn + j * 16 + (lane & 15)];
      bv[j] = b_[wn + j * 16 + (lane & 15)];
    }
#pragma unroll
    for (int i = 0; i < 4; ++i) {
#pragma unroll
      for (int r = 0; r < 4; ++r) {
        float s1 = 0.f, s2 = 0.f;
#pragma unroll
        for (int j = 0; j < 4; ++j) {
          float v = acc[i][j][r] + bi[j];
          acc[i][j][r] = v;
          s1 += v;
          s2 += v * v;
        }
#pragma unroll
        for (int d = 1; d < 16; d <<= 1) {
          s1 += __shfl_xor(s1, d);
          s2 += __shfl_xor(s2, d);
        }
        if ((lane & 15) == 0) {
          const int rl = i * 16 + ((lane >> 4) << 2) + r;
          sstat[0][w][rl] = s1;
          sstat[1][w][rl] = s2;
        }
      }
    }
    __syncthreads();
#pragma unroll
    for (int i = 0; i < 4; ++i) {
#pragma unroll
      for (int r = 0; r < 4; ++r) {
        const int rl = i * 16 + ((lane >> 4) << 2) + r;
        const float s1 = sstat[0][0][rl] + sstat[0][1][rl] + sstat[0][2][rl] + sstat[0][3][rl];
        const float s2 = sstat[1][0][rl] + sstat[1][1][rl] + sstat[1][2][rl] + sstat[1][3][rl];
        const float mu = s1 * (1.f / 256.f);
        const float var = s2 * (1.f / 256.f) - mu * mu;
        const float rs = rsqrtf(var + 1e-5f);
        const int gm = m0 + rl;
        if (gm < M) {
          const size_t base = (size_t)gm * 256 + wn + (lane & 15);
#pragma unroll
          for (int j = 0; j < 4; ++j)
            C[base + j * 16] = f2bf((acc[i][j][r] - mu) * rs * gv[j] + bv[j]);
        }
      }
    }
  } else {
#pragma unroll
    for (int i = 0; i < 4; ++i) {
      const int gm0 = m0 + i * 16 + ((lane >> 4) << 2);
#pragma unroll
      for (int r = 0; r < 4; ++r) {
        const int gm = gm0 + r;
        if (gm < M) {
          const size_t base = (size_t)gm * 256 + wn + (lane & 15);
#pragma unroll
          for (int j = 0; j < 4; ++j) {
            float v = acc[i][j][r] + bi[j];
            if (ADDZ) v += bf2f(Z[base + j * 16]);
            if (RELU) v = fmaxf(v, 0.f);
            C[base + j * 16] = f2bf(v);
          }
        }
      }
    }
  }
}

// ---------------------------------------------------------------------------
// Fold: outp (+)= sum_{k<P} betas[l0+k] * bf2f(zbase[k][i]); 8 elems/thread.
// ---------------------------------------------------------------------------
template <int WRITE>
__global__ __launch_bounds__(256) void fold_kernel(
    const ushort* __restrict__ zbase, size_t ZS, const float* __restrict__ betas,
    int l0, int P, float* __restrict__ outp, int total8) {
  const int i = blockIdx.x * 256 + threadIdx.x;
  if (i >= total8) return;
  float a[8] = {};
  for (int k = 0; k < P; ++k) {
    const float bl = betas[l0 + k];
    const uint4 u = ((const uint4*)(zbase + k * ZS))[i];
    const uint32_t ww[4] = {u.x, u.y, u.z, u.w};
#pragma unroll
    for (int q = 0; q < 4; ++q) {
      union { uint32_t u; float f; } lo, hi;
      lo.u = ww[q] << 16;
      hi.u = ww[q] & 0xffff0000u;
      a[2 * q] += bl * lo.f;
      a[2 * q + 1] += bl * hi.f;
    }
  }
  f32x4 o0 = {a[0], a[1], a[2], a[3]};
  f32x4 o1 = {a[4], a[5], a[6], a[7]};
  if (WRITE) {
    ((f32x4*)outp)[(size_t)i * 2] = o0;
    ((f32x4*)outp)[(size_t)i * 2 + 1] = o1;
  } else {
    f32x4 p0 = ((f32x4*)outp)[(size_t)i * 2];
    f32x4 p1 = ((f32x4*)outp)[(size_t)i * 2 + 1];
    ((f32x4*)outp)[(size_t)i * 2] = p0 + o0;
    ((f32x4*)outp)[(size_t)i * 2 + 1] = p1 + o1;
  }
}

// ---------------------------------------------------------------------------
// CSR build: count stores per-edge slot; fill is atomic-free scatter.
// ---------------------------------------------------------------------------
__global__ void count_kernel(const int* __restrict__ dstv, int* __restrict__ deg,
                             int* __restrict__ eoff, int E) {
  int i = blockIdx.x * 256 + threadIdx.x;
  if (i < E) eoff[i] = atomicAdd(&deg[dstv[i]], 1);
}

__global__ void scanA_kernel(const int* __restrict__ deg, int* __restrict__ excl,
                             int* __restrict__ bsum, int n) {
  __shared__ int sm[256];
  const int i = blockIdx.x * 256 + threadIdx.x;
  const int v = (i < n) ? deg[i] : 0;
  sm[threadIdx.x] = v;
  __syncthreads();
  for (int off = 1; off < 256; off <<= 1) {
    int t = (threadIdx.x >= off) ? sm[threadIdx.x - off] : 0;
    __syncthreads();
    sm[threadIdx.x] += t;
    __syncthreads();
  }
  if (i < n) excl[i] = sm[threadIdx.x] - v;
  if (threadIdx.x == 255) bsum[blockIdx.x] = sm[255];
}

__global__ void scanB_kernel(const int* __restrict__ bsum, int* __restrict__ boff, int nb) {
  __shared__ int sm[256];
  const int v = (threadIdx.x < nb) ? bsum[threadIdx.x] : 0;
  sm[threadIdx.x] = v;
  __syncthreads();
  for (int off = 1; off < 256; off <<= 1) {
    int t = (threadIdx.x >= off) ? sm[threadIdx.x - off] : 0;
    __syncthreads();
    sm[threadIdx.x] += t;
    __syncthreads();
  }
  if (threadIdx.x < nb) boff[threadIdx.x] = sm[threadIdx.x] - v;
}

__global__ void scanC_kernel(const int* __restrict__ deg, const int* __restrict__ excl,
                             const int* __restrict__ boff, int* __restrict__ rowptr,
                             float* __restrict__ invc, int n, int E) {
  const int i = blockIdx.x * 256 + threadIdx.x;
  if (i < n) {
    rowptr[i] = excl[i] + boff[blockIdx.x];
    invc[i] = 1.0f / (float)(deg[i] + 1);
  }
  if (i == 0) rowptr[n] = E;
}

__global__ void fill_kernel(const int* __restrict__ srcv, const int* __restrict__ dstv,
                            const int* __restrict__ rowptr, const int* __restrict__ eoff,
                            int* __restrict__ colv, int E) {
  int i = blockIdx.x * 256 + threadIdx.x;
  if (i < E) colv[rowptr[dstv[i]] + eoff[i]] = srcv[i];
}

// ---------------------------------------------------------------------------
// 128-d aggregation, quarter-wave (16 lanes x 16B) per node, x4 unroll.
// ---------------------------------------------------------------------------
__global__ __launch_bounds__(256) void agg128_kernel(
    const ushort* __restrict__ T, const int* __restrict__ rowptr,
    const int* __restrict__ colv, const float* __restrict__ invc,
    ushort* __restrict__ sout, int n) {
  const int node = blockIdx.x * 16 + (threadIdx.x >> 4);
  if (node >= n) return;
  const int q = threadIdx.x & 15;
  const uint4* Tv = (const uint4*)T;
  float a[8] = {}, b[8] = {}, c[8] = {}, d[8] = {};
  auto addu = [](float* acc, uint4 u) {
    const uint32_t ww[4] = {u.x, u.y, u.z, u.w};
#pragma unroll
    for (int k = 0; k < 4; ++k) {
      union { uint32_t u; float f; } lo, hi;
      lo.u = ww[k] << 16;
      hi.u = ww[k] & 0xffff0000u;
      acc[2 * k] += lo.f;
      acc[2 * k + 1] += hi.f;
    }
  };
  addu(a, Tv[(size_t)node * 16 + q]);
  const int s = rowptr[node];
  const int e = rowptr[node + 1];
  int i = s;
  for (; i + 3 < e; i += 4) {
    const uint4 u0 = Tv[(size_t)colv[i] * 16 + q];
    const uint4 u1 = Tv[(size_t)colv[i + 1] * 16 + q];
    const uint4 u2 = Tv[(size_t)colv[i + 2] * 16 + q];
    const uint4 u3 = Tv[(size_t)colv[i + 3] * 16 + q];
    addu(a, u0);
    addu(b, u1);
    addu(c, u2);
    addu(d, u3);
  }
  for (; i < e; ++i) addu(a, Tv[(size_t)colv[i] * 16 + q]);
  const float ic = invc[node];
  uint4 o;
  uint32_t* ow = (uint32_t*)&o;
#pragma unroll
  for (int k = 0; k < 4; ++k) {
    const float r0 = (a[2 * k] + b[2 * k] + c[2 * k] + d[2 * k]) * ic;
    const float r1 = (a[2 * k + 1] + b[2 * k + 1] + c[2 * k + 1] + d[2 * k + 1]) * ic;
    ow[k] = (uint32_t)f2bf(r0) | ((uint32_t)f2bf(r1) << 16);
  }
  ((uint4*)sout)[(size_t)node * 16 + q] = o;
}

__global__ void beta_kernel(const float* __restrict__ beta, float* __restrict__ betas) {
  if (threadIdx.x == 0) {
    float mx = beta[0];
    for (int i = 1; i < NLAYER + 1; ++i) mx = fmaxf(mx, beta[i]);
    float e[NLAYER + 1];
    float s = 0.f;
    for (int i = 0; i < NLAYER + 1; ++i) {
      e[i] = expf(beta[i] - mx);
      s += e[i];
    }
    const float inv = 1.f / s;
    for (int i = 0; i < NLAYER + 1; ++i) betas[i] = e[i] * inv;
  }
}

// W [L][K][N] f32 -> Wt [L][N][K] bf16 via 32x32 LDS tile (coalesced both sides)
__global__ void wconv_t(const float* __restrict__ W, ushort* __restrict__ Wt,
                        int K, int Nn) {
  __shared__ float t[32][33];
  const size_t mat = (size_t)blockIdx.z * K * Nn;
  const int kk0 = blockIdx.x * 32;
  const int nn0 = blockIdx.y * 32;
  const int tx = threadIdx.x & 31;
  const int ty = threadIdx.x >> 5;  // 0..7
#pragma unroll
  for (int i = 0; i < 4; ++i)
    t[ty * 4 + i][tx] = W[mat + (size_t)(kk0 + ty * 4 + i) * Nn + nn0 + tx];
  __syncthreads();
#pragma unroll
  for (int i = 0; i < 4; ++i)
    Wt[mat + (size_t)(nn0 + ty * 4 + i) * K + kk0 + tx] = f2bf(t[tx][ty * 4 + i]);
}

// x f32 -> bf16, 8/thread
__global__ void xcast_kernel(const float* __restrict__ x, ushort* __restrict__ xb, int n8) {
  const int i = blockIdx.x * 256 + threadIdx.x;
  if (i >= n8) return;
  const f32x4 v0 = ((const f32x4*)x)[(size_t)i * 2];
  const f32x4 v1 = ((const f32x4*)x)[(size_t)i * 2 + 1];
  bf16x8 o;
#pragma unroll
  for (int q = 0; q < 4; ++q) {
    o[q] = (short)f2bf(v0[q]);
    o[q + 4] = (short)f2bf(v1[q]);
  }
  *(bf16x8*)(xb + (size_t)i * 8) = o;
}

// Win GEMM (z0): A bf16 [M x 128], B bf16 [256 x 128], C bf16 [M x 256].
__global__ __launch_bounds__(512, 4) void gemm_win(
    const ushort* __restrict__ A, const ushort* __restrict__ B,
    const float* __restrict__ bias, ushort* __restrict__ C, int M) {
  __shared__ ushort lA[128 * 64];
  __shared__ ushort lB[256 * 64];
  const int tid = threadIdx.x;
  const int m0 = blockIdx.x * 128;
  const int lane = tid & 63;
  const int w = tid >> 6;
  const int wm = (w >> 2) * 64;
  const int wn = (w & 3) * 64;
  const int rr = tid >> 3;
  const int cc = tid & 7;
  const int ccs = cc ^ (rr & 7);
  const bool full = (m0 + 128 <= M);
  f32x4 acc[4][4] = {};
  const int K = 128;

#pragma unroll
  for (int s = 0; s < 2; ++s) {
    const int k0 = s * 64;
    if (full) {
#pragma unroll
      for (int p = 0; p < 2; ++p) {
        const int row = p * 64 + rr;
        gll16(A + (size_t)(m0 + row) * K + k0 + ccs * 8,
              lA + (size_t)(p * 64 + w * 8) * 64);
      }
    } else {
#pragma unroll
      for (int p = 0; p < 2; ++p) {
        const int row = p * 64 + rr;
        const int gm = m0 + row;
        bf16x8 av = {0, 0, 0, 0, 0, 0, 0, 0};
        if (gm < M) av = *(const bf16x8*)(A + (size_t)gm * K + k0 + cc * 8);
        const uint32_t off = (uint32_t)((row * 128 + cc * 16) ^ ((row & 7) << 4));
        *(bf16x8*)((char*)lA + off) = av;
      }
    }
#pragma unroll
    for (int p = 0; p < 4; ++p) {
      const int row = p * 64 + rr;
      gll16(B + (size_t)row * K + k0 + ccs * 8,
            lB + (size_t)(p * 64 + w * 8) * 64);
    }
    __syncthreads();
#pragma unroll
    for (int kk = 0; kk < 2; ++kk) {
      bf16x8 ah[4];
#pragma unroll
      for (int i = 0; i < 4; ++i) {
        const int arow = wm + i * 16 + (lane & 15);
        const uint32_t ao =
            (uint32_t)((arow * 128 + kk * 64 + ((lane >> 4) * 16)) ^ ((arow & 7) << 4));
        ah[i] = *(const bf16x8*)((const char*)lA + ao);
      }
#pragma unroll
      for (int j = 0; j < 4; ++j) {
        const int brow = wn + j * 16 + (lane & 15);
        const uint32_t bo =
            (uint32_t)((brow * 128 + kk * 64 + ((lane >> 4) * 16)) ^ ((brow & 7) << 4));
        const bf16x8 bv = *(const bf16x8*)((const char*)lB + bo);
#pragma unroll
        for (int i = 0; i < 4; ++i)
          acc[i][j] = __builtin_amdgcn_mfma_f32_16x16x32_bf16(ah[i], bv, acc[i][j], 0, 0, 0);
      }
    }
    __syncthreads();
  }
  float bi[4];
#pragma unroll
  for (int j = 0; j < 4; ++j) bi[j] = bias[wn + j * 16 + (lane & 15)];
#pragma unroll
  for (int i = 0; i < 4; ++i) {
    const int gm0 = m0 + wm + i * 16 + ((lane >> 4) << 2);
#pragma unroll
    for (int r = 0; r < 4; ++r) {
      const int gm = gm0 + r;
      if (gm < M) {
        const size_t base = (size_t)gm * 256 + wn + (lane & 15);
#pragma unroll
        for (int j = 0; j < 4; ++j)
          C[base + j * 16] = f2bf(acc[i][j][r] + bi[j]);
      }
    }
  }
}

// ---------------------------------------------------------------------------
extern "C" void kernel_launch(void* const* d_in, const int* in_sizes, int n_in,
                              void* d_out, int out_size, void* d_ws, size_t ws_size,
                              hipStream_t stream) {
  const float* x = (const float*)d_in[0];
  const int* eidx = (const int*)d_in[1];
  const float* Win = (const float*)d_in[2];
  const float* bin_ = (const float*)d_in[3];
  const float* W1 = (const float*)d_in[4];
  const float* b1 = (const float*)d_in[5];
  const float* W2 = (const float*)d_in[6];
  const float* b2 = (const float*)d_in[7];
  const float* U1 = (const float*)d_in[8];
  const float* c1 = (const float*)d_in[9];
  const float* U2 = (const float*)d_in[10];
  const float* c2 = (const float*)d_in[11];
  const float* ln_g = (const float*)d_in[12];
  const float* ln_b = (const float*)d_in[13];
  const float* beta = (const float*)d_in[14];
  float* outp = (float*)d_out;

  const int Nn = in_sizes[0] / 128;  // 50000
  const int E = in_sizes[1] / 2;     // 800000
  const int* srcv = eidx;
  const int* dstv = eidx + E;

  char* p = (char*)d_ws;
  auto alloc = [&](size_t bytes) {
    char* r = p;
    p += (bytes + 255) & ~(size_t)255;
    return r;
  };
  ushort* hbuf = (ushort*)alloc((size_t)Nn * HIDC * 2);  // h bf16
  ushort* TSO = (ushort*)alloc((size_t)Nn * HIDC * 2);   // T | s, later O
  ushort* xbf = (ushort*)alloc((size_t)Nn * 128 * 2);
  ushort* WinT = (ushort*)alloc(128 * 256 * 2);
  ushort* W1T = (ushort*)alloc((size_t)NLAYER * 256 * 128 * 2);
  ushort* W2T = (ushort*)alloc((size_t)NLAYER * 128 * 256 * 2);
  ushort* U1T = (ushort*)alloc((size_t)NLAYER * 256 * 256 * 2);
  ushort* U2T = (ushort*)alloc((size_t)NLAYER * 256 * 256 * 2);
  int* deg = (int*)alloc((size_t)Nn * 4);
  int* rowptr = (int*)alloc((size_t)(Nn + 1) * 4);
  float* invc = (float*)alloc((size_t)Nn * 4);
  int* colv = (int*)alloc((size_t)E * 4);
  int* eoff = (int*)alloc((size_t)E * 4);
  int* excl = (int*)alloc((size_t)Nn * 4);
  int* bsum = (int*)alloc(256 * 4);
  int* boff = (int*)alloc(256 * 4);
  float* betas = (float*)alloc(64);

  // z-history slots: as many as fit (G in [2, 11])
  const size_t ZS = (size_t)Nn * HIDC;
  const size_t slotB = ZS * 2;
  const size_t used = (size_t)(p - (char*)d_ws);
  int G = 2;
  if (ws_size > used + 4096) {
    size_t fit = (ws_size - used - 4096) / (slotB + 256);
    G = (int)(fit < 2 ? 2 : (fit > NLAYER + 1 ? NLAYER + 1 : fit));
  }
  ushort* zbase = (ushort*)alloc((size_t)G * slotB);

  ushort* T128 = TSO;
  ushort* s128 = TSO + (size_t)Nn * MSGC;
  ushort* Obuf = TSO;  // reuses T|s after both consumed

  const int nscan = (Nn + 255) / 256;
  const int mb128 = (Nn + 127) / 128;
  const int mb64 = (Nn + 63) / 64;
  const int nagg = (Nn + 15) / 16;
  const int total8 = (Nn * HIDC) / 8;

  hipMemsetAsync(deg, 0, (size_t)Nn * 4, stream);
  count_kernel<<<(E + 255) / 256, 256, 0, stream>>>(dstv, deg, eoff, E);
  scanA_kernel<<<nscan, 256, 0, stream>>>(deg, excl, bsum, Nn);
  scanB_kernel<<<1, 256, 0, stream>>>(bsum, boff, nscan);
  scanC_kernel<<<nscan, 256, 0, stream>>>(deg, excl, boff, rowptr, invc, Nn, E);
  fill_kernel<<<(E + 255) / 256, 256, 0, stream>>>(srcv, dstv, rowptr, eoff, colv, E);
  beta_kernel<<<1, 64, 0, stream>>>(beta, betas);
  xcast_kernel<<<(Nn * 16 + 255) / 256, 256, 0, stream>>>(x, xbf, Nn * 16);
  wconv_t<<<dim3(4, 8, 1), 256, 0, stream>>>(Win, WinT, 128, 256);
  wconv_t<<<dim3(8, 4, NLAYER), 256, 0, stream>>>(W1, W1T, 256, 128);
  wconv_t<<<dim3(4, 8, NLAYER), 256, 0, stream>>>(W2, W2T, 128, 256);
  wconv_t<<<dim3(8, 8, NLAYER), 256, 0, stream>>>(U1, U1T, 256, 256);
  wconv_t<<<dim3(8, 8, NLAYER), 256, 0, stream>>>(U2, U2T, 256, 256);

  // fold bookkeeping
  int pend = 0, l0 = 0;
  bool first = true;
  auto flush = [&]() {
    if (pend > 0) {
      if (first)
        fold_kernel<1><<<(total8 + 255) / 256, 256, 0, stream>>>(zbase, ZS, betas, l0,
                                                                 pend, outp, total8);
      else
        fold_kernel<0><<<(total8 + 255) / 256, 256, 0, stream>>>(zbase, ZS, betas, l0,
                                                                 pend, outp, total8);
      first = false;
      l0 += pend;
      pend = 0;
    }
  };

  // z0 = x @ Win + bin -> slot 0
  ushort* zcur = zbase;
  gemm_win<<<mb128, 512, 0, stream>>>(xbf, WinT, bin_, zcur, Nn);
  pend = 1;

  for (int l = 0; l < NLAYER; ++l) {
    // T = bf16(relu(z @ W1 + b1))
    gemm_w1_64<<<mb64, 256, 0, stream>>>(zcur, W1T + (size_t)l * 256 * 128,
                                         b1 + l * 128, T128, Nn);
    // s = bf16(segmean(T))
    agg128_kernel<<<nagg, 256, 0, stream>>>(T128, rowptr, colv, invc, s128, Nn);
    // h = bf16(z + s @ W2 + b2)
    gemm_big64<0, 1, 0><<<mb64, 256, 0, stream>>>(s128, W2T + (size_t)l * 128 * 256,
                                                  b2 + l * 256, zcur, hbuf, nullptr,
                                                  nullptr, Nn, 128);
    // O = bf16(relu(h @ U1 + c1))
    gemm_big64<1, 0, 0><<<mb64, 256, 0, stream>>>(hbuf, U1T + (size_t)l * 256 * 256,
                                                  c1 + l * 256, nullptr, Obuf, nullptr,
                                                  nullptr, Nn, 256);
    // fold if all slots full
    if (pend == G) flush();
    // z' = bf16(LN(O @ U2 + c2)*g + b)
    ushort* znext = zbase + (size_t)pend * ZS;
    gemm_big64<0, 0, 1><<<mb64, 256, 0, stream>>>(Obuf, U2T + (size_t)l * 256 * 256,
                                                  c2 + l * 256, nullptr, znext,
                                                  ln_g + l * 256, ln_b + l * 256, Nn, 256);
    zcur = znext;
    pend++;
  }
  flush();
}

// Round 14
// 1247.387 us; speedup vs baseline: 1.0205x; 1.0205x over previous
//
#include <hip/hip_runtime.h>
#include <stdint.h>

typedef __attribute__((ext_vector_type(4))) float f32x4;
typedef __attribute__((ext_vector_type(8))) short bf16x8;

#define HIDC 256
#define MSGC 128
#define NLAYER 10

__device__ __forceinline__ ushort f2bf(float f) {
  union { float f; uint32_t u; } a; a.f = f;
  uint32_t u = a.u;
  return (ushort)((u + 0x7fffu + ((u >> 16) & 1u)) >> 16);
}
__device__ __forceinline__ float bf2f(ushort h) {
  union { float f; uint32_t u; } a; a.u = ((uint32_t)h) << 16;
  return a.f;
}

// async global->LDS, 16B per lane; dst is wave-uniform base (lane*16 added by HW)
__device__ __forceinline__ void gll16(const void* g, void* l) {
  __builtin_amdgcn_global_load_lds(
      (const __attribute__((address_space(1))) void*)g,
      (__attribute__((address_space(3))) void*)l, 16, 0, 0);
}

// ---------------------------------------------------------------------------
// W1 GEMM: A bf16 [M x 256], B bf16 [128 x 256](T), C bf16 [M x 128].
// Tile 64x128, 4 waves, BK=64, RELU fused. 24 KB LDS -> 6 blocks/CU.
// ---------------------------------------------------------------------------
__global__ __launch_bounds__(256, 6) void gemm_w1_64(
    const ushort* __restrict__ A, const ushort* __restrict__ B,
    const float* __restrict__ bias, ushort* __restrict__ C, int M) {
  __shared__ ushort lA[64 * 64];
  __shared__ ushort lB[128 * 64];
  const int tid = threadIdx.x;
  const int m0 = blockIdx.x * 64;
  const int lane = tid & 63;
  const int w = tid >> 6;
  const int wm = (w >> 1) * 32;  // 0,32
  const int wn = (w & 1) * 64;   // 0,64
  const int rr = tid >> 3;       // 0..31
  const int cc = tid & 7;        // 0..7
  const int ccs = cc ^ (rr & 7);
  const bool full = (m0 + 64 <= M);
  f32x4 acc[2][4] = {};

#pragma unroll
  for (int s = 0; s < 4; ++s) {  // K = 256
    const int k0 = s * 64;
    if (full) {
#pragma unroll
      for (int p = 0; p < 2; ++p) {
        const int row = p * 32 + rr;
        gll16(A + (size_t)(m0 + row) * 256 + k0 + ccs * 8,
              lA + (size_t)(p * 32 + w * 8) * 64);
      }
    } else {
#pragma unroll
      for (int p = 0; p < 2; ++p) {
        const int row = p * 32 + rr;
        const int gm = m0 + row;
        bf16x8 av = {0, 0, 0, 0, 0, 0, 0, 0};
        if (gm < M) av = *(const bf16x8*)(A + (size_t)gm * 256 + k0 + cc * 8);
        const uint32_t off = (uint32_t)((row * 128 + cc * 16) ^ ((row & 7) << 4));
        *(bf16x8*)((char*)lA + off) = av;
      }
    }
#pragma unroll
    for (int p = 0; p < 4; ++p) {
      const int row = p * 32 + rr;
      gll16(B + (size_t)row * 256 + k0 + ccs * 8,
            lB + (size_t)(p * 32 + w * 8) * 64);
    }
    __syncthreads();
#pragma unroll
    for (int kk = 0; kk < 2; ++kk) {
      bf16x8 ah[2];
#pragma unroll
      for (int i = 0; i < 2; ++i) {
        const int arow = wm + i * 16 + (lane & 15);
        const uint32_t ao =
            (uint32_t)((arow * 128 + kk * 64 + ((lane >> 4) * 16)) ^ ((arow & 7) << 4));
        ah[i] = *(const bf16x8*)((const char*)lA + ao);
      }
#pragma unroll
      for (int j = 0; j < 4; ++j) {
        const int brow = wn + j * 16 + (lane & 15);
        const uint32_t bo =
            (uint32_t)((brow * 128 + kk * 64 + ((lane >> 4) * 16)) ^ ((brow & 7) << 4));
        const bf16x8 bv = *(const bf16x8*)((const char*)lB + bo);
#pragma unroll
        for (int i = 0; i < 2; ++i)
          acc[i][j] = __builtin_amdgcn_mfma_f32_16x16x32_bf16(ah[i], bv, acc[i][j], 0, 0, 0);
      }
    }
    __syncthreads();
  }
  float bi[4];
#pragma unroll
  for (int j = 0; j < 4; ++j) bi[j] = bias[wn + j * 16 + (lane & 15)];
#pragma unroll
  for (int i = 0; i < 2; ++i) {
    const int gm0 = m0 + wm + i * 16 + ((lane >> 4) << 2);
#pragma unroll
    for (int r = 0; r < 4; ++r) {
      const int gm = gm0 + r;
      if (gm < M) {
        const size_t base = (size_t)gm * 128 + wn + (lane & 15);
#pragma unroll
        for (int j = 0; j < 4; ++j)
          C[base + j * 16] = f2bf(fmaxf(acc[i][j][r] + bi[j], 0.f));
      }
    }
  }
}

// ---------------------------------------------------------------------------
// Big GEMM 64-row, double-buffered: A bf16 [M x K], B bf16 [256 x K],
// tile 64x256, 4 waves, BK=32, 2-phase prefetch. LDS carved to EXACTLY
// 40 KB (sstat overlaid on lA after compute) -> 4 blocks/CU.
// LN=0: C = bf16(act(A@B^T + bias [+Z]));  LN=1: C = bf16(LN(..)*g+b_)
// ---------------------------------------------------------------------------
template <int RELU, int ADDZ, int LN>
__global__ __launch_bounds__(256, 4) void gemm_big64(
    const ushort* __restrict__ A, const ushort* __restrict__ B,
    const float* __restrict__ bias, const ushort* __restrict__ Z,
    ushort* __restrict__ C, const float* __restrict__ g,
    const float* __restrict__ b_, int M, int K) {
  __shared__ char smem[40960];  // [0,8K) lA[2] | [8K,40K) lB[2]
  ushort* lAbase = (ushort*)smem;               // 2 x 64*32
  ushort* lBbase = (ushort*)(smem + 8192);      // 2 x 256*32
  float* sstat = (float*)smem;                  // overlay [2][4][64], epilogue only
  const int tid = threadIdx.x;
  const int m0 = blockIdx.x * 64;
  const int lane = tid & 63;
  const int w = tid >> 6;    // 0..3
  const int wn = w * 64;     // col slice per wave
  const int srow = tid >> 2; // 0..63 (stage row)
  const int scc = tid & 3;   // 16B chunk within 64B row
  const bool full = (m0 + 64 <= M);
  f32x4 acc[4][4] = {};
  const int nsteps = K >> 5;

  auto stage = [&](int s, int buf) {
    const int k0 = s * 32;
    ushort* lA = lAbase + buf * 64 * 32;
    ushort* lB = lBbase + buf * 256 * 32;
    if (full) {
      const int ccs = scc ^ ((srow >> 1) & 3);
      gll16(A + (size_t)(m0 + srow) * K + k0 + ccs * 8, lA + (w * 16) * 32);
    } else {
      const int gm = m0 + srow;
      bf16x8 av = {0, 0, 0, 0, 0, 0, 0, 0};
      if (gm < M) av = *(const bf16x8*)(A + (size_t)gm * K + k0 + scc * 8);
      const uint32_t off = (uint32_t)((srow * 64 + scc * 16) ^ ((srow & 6) << 3));
      *(bf16x8*)((char*)lA + off) = av;
    }
#pragma unroll
    for (int p = 0; p < 4; ++p) {
      const int row = p * 64 + srow;
      const int ccs = scc ^ ((row >> 1) & 3);
      gll16(B + (size_t)row * K + k0 + ccs * 8, lB + (p * 64 + w * 16) * 32);
    }
  };

  int cur = 0;
  stage(0, 0);
  for (int s = 0; s < nsteps; ++s) {
    __syncthreads();
    if (s + 1 < nsteps) stage(s + 1, cur ^ 1);
    const ushort* lA = lAbase + cur * 64 * 32;
    const ushort* lB = lBbase + cur * 256 * 32;
    bf16x8 ah[4];
#pragma unroll
    for (int i = 0; i < 4; ++i) {
      const int arow = i * 16 + (lane & 15);
      const uint32_t ao =
          (uint32_t)((arow * 64 + ((lane >> 4) * 16)) ^ ((arow & 6) << 3));
      ah[i] = *(const bf16x8*)((const char*)lA + ao);
    }
    __builtin_amdgcn_s_setprio(1);
#pragma unroll
    for (int j = 0; j < 4; ++j) {
      const int brow = wn + j * 16 + (lane & 15);
      const uint32_t bo =
          (uint32_t)((brow * 64 + ((lane >> 4) * 16)) ^ ((brow & 6) << 3));
      const bf16x8 bv = *(const bf16x8*)((const char*)lB + bo);
#pragma unroll
      for (int i = 0; i < 4; ++i)
        acc[i][j] = __builtin_amdgcn_mfma_f32_16x16x32_bf16(ah[i], bv, acc[i][j], 0, 0, 0);
    }
    __builtin_amdgcn_s_setprio(0);
    cur ^= 1;
  }
  __syncthreads();

  float bi[4];
#pragma unroll
  for (int j = 0; j < 4; ++j) bi[j] = bias[wn + j * 16 + (lane & 15)];

  if (LN) {
    float gv[4], bv[4];
#pragma unroll
    for (int j = 0; j < 4; ++j) {
      gv[j] = g[wn + j * 16 + (lane & 15)];
      bv[j] = b_[wn + j * 16 + (lane & 15)];
    }
#pragma unroll
    for (int i = 0; i < 4; ++i) {
#pragma unroll
      for (int r = 0; r < 4; ++r) {
        float s1 = 0.f, s2 = 0.f;
#pragma unroll
        for (int j = 0; j < 4; ++j) {
          float v = acc[i][j][r] + bi[j];
          acc[i][j][r] = v;
          s1 += v;
          s2 += v * v;
        }
#pragma unroll
        for (int d = 1; d < 16; d <<= 1) {
          s1 += __shfl_xor(s1, d);
          s2 += __shfl_xor(s2, d);
        }
        if ((lane & 15) == 0) {
          const int rl = i * 16 + ((lane >> 4) << 2) + r;
          sstat[(0 * 4 + w) * 64 + rl] = s1;
          sstat[(1 * 4 + w) * 64 + rl] = s2;
        }
      }
    }
    __syncthreads();
#pragma unroll
    for (int i = 0; i < 4; ++i) {
#pragma unroll
      for (int r = 0; r < 4; ++r) {
        const int rl = i * 16 + ((lane >> 4) << 2) + r;
        const float s1 = sstat[0 * 256 + 0 * 64 + rl] + sstat[0 * 256 + 1 * 64 + rl] +
                         sstat[0 * 256 + 2 * 64 + rl] + sstat[0 * 256 + 3 * 64 + rl];
        const float s2 = sstat[1 * 256 + 0 * 64 + rl] + sstat[1 * 256 + 1 * 64 + rl] +
                         sstat[1 * 256 + 2 * 64 + rl] + sstat[1 * 256 + 3 * 64 + rl];
        const float mu = s1 * (1.f / 256.f);
        const float var = s2 * (1.f / 256.f) - mu * mu;
        const float rs = rsqrtf(var + 1e-5f);
        const int gm = m0 + rl;
        if (gm < M) {
          const size_t base = (size_t)gm * 256 + wn + (lane & 15);
#pragma unroll
          for (int j = 0; j < 4; ++j)
            C[base + j * 16] = f2bf((acc[i][j][r] - mu) * rs * gv[j] + bv[j]);
        }
      }
    }
  } else {
#pragma unroll
    for (int i = 0; i < 4; ++i) {
      const int gm0 = m0 + i * 16 + ((lane >> 4) << 2);
#pragma unroll
      for (int r = 0; r < 4; ++r) {
        const int gm = gm0 + r;
        if (gm < M) {
          const size_t base = (size_t)gm * 256 + wn + (lane & 15);
#pragma unroll
          for (int j = 0; j < 4; ++j) {
            float v = acc[i][j][r] + bi[j];
            if (ADDZ) v += bf2f(Z[base + j * 16]);
            if (RELU) v = fmaxf(v, 0.f);
            C[base + j * 16] = f2bf(v);
          }
        }
      }
    }
  }
}

// ---------------------------------------------------------------------------
// Fold: outp (+)= sum_{k<P} betas[l0+k] * bf2f(zbase[k][i]); 8 elems/thread.
// ---------------------------------------------------------------------------
template <int WRITE>
__global__ __launch_bounds__(256) void fold_kernel(
    const ushort* __restrict__ zbase, size_t ZS, const float* __restrict__ betas,
    int l0, int P, float* __restrict__ outp, int total8) {
  const int i = blockIdx.x * 256 + threadIdx.x;
  if (i >= total8) return;
  float a[8] = {};
  for (int k = 0; k < P; ++k) {
    const float bl = betas[l0 + k];
    const uint4 u = ((const uint4*)(zbase + k * ZS))[i];
    const uint32_t ww[4] = {u.x, u.y, u.z, u.w};
#pragma unroll
    for (int q = 0; q < 4; ++q) {
      union { uint32_t u; float f; } lo, hi;
      lo.u = ww[q] << 16;
      hi.u = ww[q] & 0xffff0000u;
      a[2 * q] += bl * lo.f;
      a[2 * q + 1] += bl * hi.f;
    }
  }
  f32x4 o0 = {a[0], a[1], a[2], a[3]};
  f32x4 o1 = {a[4], a[5], a[6], a[7]};
  if (WRITE) {
    ((f32x4*)outp)[(size_t)i * 2] = o0;
    ((f32x4*)outp)[(size_t)i * 2 + 1] = o1;
  } else {
    f32x4 p0 = ((f32x4*)outp)[(size_t)i * 2];
    f32x4 p1 = ((f32x4*)outp)[(size_t)i * 2 + 1];
    ((f32x4*)outp)[(size_t)i * 2] = p0 + o0;
    ((f32x4*)outp)[(size_t)i * 2 + 1] = p1 + o1;
  }
}

// ---------------------------------------------------------------------------
// CSR build: count stores per-edge slot; fill is atomic-free scatter.
// ---------------------------------------------------------------------------
__global__ void count_kernel(const int* __restrict__ dstv, int* __restrict__ deg,
                             int* __restrict__ eoff, int E) {
  int i = blockIdx.x * 256 + threadIdx.x;
  if (i < E) eoff[i] = atomicAdd(&deg[dstv[i]], 1);
}

__global__ void scanA_kernel(const int* __restrict__ deg, int* __restrict__ excl,
                             int* __restrict__ bsum, int n) {
  __shared__ int sm[256];
  const int i = blockIdx.x * 256 + threadIdx.x;
  const int v = (i < n) ? deg[i] : 0;
  sm[threadIdx.x] = v;
  __syncthreads();
  for (int off = 1; off < 256; off <<= 1) {
    int t = (threadIdx.x >= off) ? sm[threadIdx.x - off] : 0;
    __syncthreads();
    sm[threadIdx.x] += t;
    __syncthreads();
  }
  if (i < n) excl[i] = sm[threadIdx.x] - v;
  if (threadIdx.x == 255) bsum[blockIdx.x] = sm[255];
}

__global__ void scanB_kernel(const int* __restrict__ bsum, int* __restrict__ boff, int nb) {
  __shared__ int sm[256];
  const int v = (threadIdx.x < nb) ? bsum[threadIdx.x] : 0;
  sm[threadIdx.x] = v;
  __syncthreads();
  for (int off = 1; off < 256; off <<= 1) {
    int t = (threadIdx.x >= off) ? sm[threadIdx.x - off] : 0;
    __syncthreads();
    sm[threadIdx.x] += t;
    __syncthreads();
  }
  if (threadIdx.x < nb) boff[threadIdx.x] = sm[threadIdx.x] - v;
}

__global__ void scanC_kernel(const int* __restrict__ deg, const int* __restrict__ excl,
                             const int* __restrict__ boff, int* __restrict__ rowptr,
                             float* __restrict__ invc, int n, int E) {
  const int i = blockIdx.x * 256 + threadIdx.x;
  if (i < n) {
    rowptr[i] = excl[i] + boff[blockIdx.x];
    invc[i] = 1.0f / (float)(deg[i] + 1);
  }
  if (i == 0) rowptr[n] = E;
}

__global__ void fill_kernel(const int* __restrict__ srcv, const int* __restrict__ dstv,
                            const int* __restrict__ rowptr, const int* __restrict__ eoff,
                            int* __restrict__ colv, int E) {
  int i = blockIdx.x * 256 + threadIdx.x;
  if (i < E) colv[rowptr[dstv[i]] + eoff[i]] = srcv[i];
}

// ---------------------------------------------------------------------------
// 128-d aggregation, quarter-wave (16 lanes x 16B) per node, x4 unroll.
// ---------------------------------------------------------------------------
__global__ __launch_bounds__(256) void agg128_kernel(
    const ushort* __restrict__ T, const int* __restrict__ rowptr,
    const int* __restrict__ colv, const float* __restrict__ invc,
    ushort* __restrict__ sout, int n) {
  const int node = blockIdx.x * 16 + (threadIdx.x >> 4);
  if (node >= n) return;
  const int q = threadIdx.x & 15;
  const uint4* Tv = (const uint4*)T;
  float a[8] = {}, b[8] = {}, c[8] = {}, d[8] = {};
  auto addu = [](float* acc, uint4 u) {
    const uint32_t ww[4] = {u.x, u.y, u.z, u.w};
#pragma unroll
    for (int k = 0; k < 4; ++k) {
      union { uint32_t u; float f; } lo, hi;
      lo.u = ww[k] << 16;
      hi.u = ww[k] & 0xffff0000u;
      acc[2 * k] += lo.f;
      acc[2 * k + 1] += hi.f;
    }
  };
  addu(a, Tv[(size_t)node * 16 + q]);
  const int s = rowptr[node];
  const int e = rowptr[node + 1];
  int i = s;
  for (; i + 3 < e; i += 4) {
    const uint4 u0 = Tv[(size_t)colv[i] * 16 + q];
    const uint4 u1 = Tv[(size_t)colv[i + 1] * 16 + q];
    const uint4 u2 = Tv[(size_t)colv[i + 2] * 16 + q];
    const uint4 u3 = Tv[(size_t)colv[i + 3] * 16 + q];
    addu(a, u0);
    addu(b, u1);
    addu(c, u2);
    addu(d, u3);
  }
  for (; i < e; ++i) addu(a, Tv[(size_t)colv[i] * 16 + q]);
  const float ic = invc[node];
  uint4 o;
  uint32_t* ow = (uint32_t*)&o;
#pragma unroll
  for (int k = 0; k < 4; ++k) {
    const float r0 = (a[2 * k] + b[2 * k] + c[2 * k] + d[2 * k]) * ic;
    const float r1 = (a[2 * k + 1] + b[2 * k + 1] + c[2 * k + 1] + d[2 * k + 1]) * ic;
    ow[k] = (uint32_t)f2bf(r0) | ((uint32_t)f2bf(r1) << 16);
  }
  ((uint4*)sout)[(size_t)node * 16 + q] = o;
}

__global__ void beta_kernel(const float* __restrict__ beta, float* __restrict__ betas) {
  if (threadIdx.x == 0) {
    float mx = beta[0];
    for (int i = 1; i < NLAYER + 1; ++i) mx = fmaxf(mx, beta[i]);
    float e[NLAYER + 1];
    float s = 0.f;
    for (int i = 0; i < NLAYER + 1; ++i) {
      e[i] = expf(beta[i] - mx);
      s += e[i];
    }
    const float inv = 1.f / s;
    for (int i = 0; i < NLAYER + 1; ++i) betas[i] = e[i] * inv;
  }
}

// W [L][K][N] f32 -> Wt [L][N][K] bf16 via 32x32 LDS tile
__global__ void wconv_t(const float* __restrict__ W, ushort* __restrict__ Wt,
                        int K, int Nn) {
  __shared__ float t[32][33];
  const size_t mat = (size_t)blockIdx.z * K * Nn;
  const int kk0 = blockIdx.x * 32;
  const int nn0 = blockIdx.y * 32;
  const int tx = threadIdx.x & 31;
  const int ty = threadIdx.x >> 5;  // 0..7
#pragma unroll
  for (int i = 0; i < 4; ++i)
    t[ty * 4 + i][tx] = W[mat + (size_t)(kk0 + ty * 4 + i) * Nn + nn0 + tx];
  __syncthreads();
#pragma unroll
  for (int i = 0; i < 4; ++i)
    Wt[mat + (size_t)(nn0 + ty * 4 + i) * K + kk0 + tx] = f2bf(t[tx][ty * 4 + i]);
}

// x f32 -> bf16, 8/thread
__global__ void xcast_kernel(const float* __restrict__ x, ushort* __restrict__ xb, int n8) {
  const int i = blockIdx.x * 256 + threadIdx.x;
  if (i >= n8) return;
  const f32x4 v0 = ((const f32x4*)x)[(size_t)i * 2];
  const f32x4 v1 = ((const f32x4*)x)[(size_t)i * 2 + 1];
  bf16x8 o;
#pragma unroll
  for (int q = 0; q < 4; ++q) {
    o[q] = (short)f2bf(v0[q]);
    o[q + 4] = (short)f2bf(v1[q]);
  }
  *(bf16x8*)(xb + (size_t)i * 8) = o;
}

// Win GEMM (z0): A bf16 [M x 128], B bf16 [256 x 128], C bf16 [M x 256].
__global__ __launch_bounds__(512, 4) void gemm_win(
    const ushort* __restrict__ A, const ushort* __restrict__ B,
    const float* __restrict__ bias, ushort* __restrict__ C, int M) {
  __shared__ ushort lA[128 * 64];
  __shared__ ushort lB[256 * 64];
  const int tid = threadIdx.x;
  const int m0 = blockIdx.x * 128;
  const int lane = tid & 63;
  const int w = tid >> 6;
  const int wm = (w >> 2) * 64;
  const int wn = (w & 3) * 64;
  const int rr = tid >> 3;
  const int cc = tid & 7;
  const int ccs = cc ^ (rr & 7);
  const bool full = (m0 + 128 <= M);
  f32x4 acc[4][4] = {};
  const int K = 128;

#pragma unroll
  for (int s = 0; s < 2; ++s) {
    const int k0 = s * 64;
    if (full) {
#pragma unroll
      for (int p = 0; p < 2; ++p) {
        const int row = p * 64 + rr;
        gll16(A + (size_t)(m0 + row) * K + k0 + ccs * 8,
              lA + (size_t)(p * 64 + w * 8) * 64);
      }
    } else {
#pragma unroll
      for (int p = 0; p < 2; ++p) {
        const int row = p * 64 + rr;
        const int gm = m0 + row;
        bf16x8 av = {0, 0, 0, 0, 0, 0, 0, 0};
        if (gm < M) av = *(const bf16x8*)(A + (size_t)gm * K + k0 + cc * 8);
        const uint32_t off = (uint32_t)((row * 128 + cc * 16) ^ ((row & 7) << 4));
        *(bf16x8*)((char*)lA + off) = av;
      }
    }
#pragma unroll
    for (int p = 0; p < 4; ++p) {
      const int row = p * 64 + rr;
      gll16(B + (size_t)row * K + k0 + ccs * 8,
            lB + (size_t)(p * 64 + w * 8) * 64);
    }
    __syncthreads();
#pragma unroll
    for (int kk = 0; kk < 2; ++kk) {
      bf16x8 ah[4];
#pragma unroll
      for (int i = 0; i < 4; ++i) {
        const int arow = wm + i * 16 + (lane & 15);
        const uint32_t ao =
            (uint32_t)((arow * 128 + kk * 64 + ((lane >> 4) * 16)) ^ ((arow & 7) << 4));
        ah[i] = *(const bf16x8*)((const char*)lA + ao);
      }
#pragma unroll
      for (int j = 0; j < 4; ++j) {
        const int brow = wn + j * 16 + (lane & 15);
        const uint32_t bo =
            (uint32_t)((brow * 128 + kk * 64 + ((lane >> 4) * 16)) ^ ((brow & 7) << 4));
        const bf16x8 bv = *(const bf16x8*)((const char*)lB + bo);
#pragma unroll
        for (int i = 0; i < 4; ++i)
          acc[i][j] = __builtin_amdgcn_mfma_f32_16x16x32_bf16(ah[i], bv, acc[i][j], 0, 0, 0);
      }
    }
    __syncthreads();
  }
  float bi[4];
#pragma unroll
  for (int j = 0; j < 4; ++j) bi[j] = bias[wn + j * 16 + (lane & 15)];
#pragma unroll
  for (int i = 0; i < 4; ++i) {
    const int gm0 = m0 + wm + i * 16 + ((lane >> 4) << 2);
#pragma unroll
    for (int r = 0; r < 4; ++r) {
      const int gm = gm0 + r;
      if (gm < M) {
        const size_t base = (size_t)gm * 256 + wn + (lane & 15);
#pragma unroll
        for (int j = 0; j < 4; ++j)
          C[base + j * 16] = f2bf(acc[i][j][r] + bi[j]);
      }
    }
  }
}

// ---------------------------------------------------------------------------
extern "C" void kernel_launch(void* const* d_in, const int* in_sizes, int n_in,
                              void* d_out, int out_size, void* d_ws, size_t ws_size,
                              hipStream_t stream) {
  const float* x = (const float*)d_in[0];
  const int* eidx = (const int*)d_in[1];
  const float* Win = (const float*)d_in[2];
  const float* bin_ = (const float*)d_in[3];
  const float* W1 = (const float*)d_in[4];
  const float* b1 = (const float*)d_in[5];
  const float* W2 = (const float*)d_in[6];
  const float* b2 = (const float*)d_in[7];
  const float* U1 = (const float*)d_in[8];
  const float* c1 = (const float*)d_in[9];
  const float* U2 = (const float*)d_in[10];
  const float* c2 = (const float*)d_in[11];
  const float* ln_g = (const float*)d_in[12];
  const float* ln_b = (const float*)d_in[13];
  const float* beta = (const float*)d_in[14];
  float* outp = (float*)d_out;

  const int Nn = in_sizes[0] / 128;  // 50000
  const int E = in_sizes[1] / 2;     // 800000
  const int* srcv = eidx;
  const int* dstv = eidx + E;

  char* p = (char*)d_ws;
  auto alloc = [&](size_t bytes) {
    char* r = p;
    p += (bytes + 255) & ~(size_t)255;
    return r;
  };
  ushort* hbuf = (ushort*)alloc((size_t)Nn * HIDC * 2);  // h bf16
  ushort* TSO = (ushort*)alloc((size_t)Nn * HIDC * 2);   // T | s, later O
  ushort* xbf = (ushort*)alloc((size_t)Nn * 128 * 2);
  ushort* WinT = (ushort*)alloc(128 * 256 * 2);
  ushort* W1T = (ushort*)alloc((size_t)NLAYER * 256 * 128 * 2);
  ushort* W2T = (ushort*)alloc((size_t)NLAYER * 128 * 256 * 2);
  ushort* U1T = (ushort*)alloc((size_t)NLAYER * 256 * 256 * 2);
  ushort* U2T = (ushort*)alloc((size_t)NLAYER * 256 * 256 * 2);
  int* deg = (int*)alloc((size_t)Nn * 4);
  int* rowptr = (int*)alloc((size_t)(Nn + 1) * 4);
  float* invc = (float*)alloc((size_t)Nn * 4);
  int* colv = (int*)alloc((size_t)E * 4);
  int* eoff = (int*)alloc((size_t)E * 4);
  int* excl = (int*)alloc((size_t)Nn * 4);
  int* bsum = (int*)alloc(256 * 4);
  int* boff = (int*)alloc(256 * 4);
  float* betas = (float*)alloc(64);

  // z-history slots: as many as fit (G in [2, 11])
  const size_t ZS = (size_t)Nn * HIDC;
  const size_t slotB = ZS * 2;
  const size_t used = (size_t)(p - (char*)d_ws);
  int G = 2;
  if (ws_size > used + 4096) {
    size_t fit = (ws_size - used - 4096) / (slotB + 256);
    G = (int)(fit < 2 ? 2 : (fit > NLAYER + 1 ? NLAYER + 1 : fit));
  }
  ushort* zbase = (ushort*)alloc((size_t)G * slotB);

  ushort* T128 = TSO;
  ushort* s128 = TSO + (size_t)Nn * MSGC;
  ushort* Obuf = TSO;  // reuses T|s after both consumed

  const int nscan = (Nn + 255) / 256;
  const int mb128 = (Nn + 127) / 128;
  const int mb64 = (Nn + 63) / 64;
  const int nagg = (Nn + 15) / 16;
  const int total8 = (Nn * HIDC) / 8;

  hipMemsetAsync(deg, 0, (size_t)Nn * 4, stream);
  count_kernel<<<(E + 255) / 256, 256, 0, stream>>>(dstv, deg, eoff, E);
  scanA_kernel<<<nscan, 256, 0, stream>>>(deg, excl, bsum, Nn);
  scanB_kernel<<<1, 256, 0, stream>>>(bsum, boff, nscan);
  scanC_kernel<<<nscan, 256, 0, stream>>>(deg, excl, boff, rowptr, invc, Nn, E);
  fill_kernel<<<(E + 255) / 256, 256, 0, stream>>>(srcv, dstv, rowptr, eoff, colv, E);
  beta_kernel<<<1, 64, 0, stream>>>(beta, betas);
  xcast_kernel<<<(Nn * 16 + 255) / 256, 256, 0, stream>>>(x, xbf, Nn * 16);
  wconv_t<<<dim3(4, 8, 1), 256, 0, stream>>>(Win, WinT, 128, 256);
  wconv_t<<<dim3(8, 4, NLAYER), 256, 0, stream>>>(W1, W1T, 256, 128);
  wconv_t<<<dim3(4, 8, NLAYER), 256, 0, stream>>>(W2, W2T, 128, 256);
  wconv_t<<<dim3(8, 8, NLAYER), 256, 0, stream>>>(U1, U1T, 256, 256);
  wconv_t<<<dim3(8, 8, NLAYER), 256, 0, stream>>>(U2, U2T, 256, 256);

  // fold bookkeeping
  int pend = 0, l0 = 0;
  bool first = true;
  auto flush = [&]() {
    if (pend > 0) {
      if (first)
        fold_kernel<1><<<(total8 + 255) / 256, 256, 0, stream>>>(zbase, ZS, betas, l0,
                                                                 pend, outp, total8);
      else
        fold_kernel<0><<<(total8 + 255) / 256, 256, 0, stream>>>(zbase, ZS, betas, l0,
                                                                 pend, outp, total8);
      first = false;
      l0 += pend;
      pend = 0;
    }
  };

  // z0 = x @ Win + bin -> slot 0
  ushort* zcur = zbase;
  gemm_win<<<mb128, 512, 0, stream>>>(xbf, WinT, bin_, zcur, Nn);
  pend = 1;

  for (int l = 0; l < NLAYER; ++l) {
    // T = bf16(relu(z @ W1 + b1))
    gemm_w1_64<<<mb64, 256, 0, stream>>>(zcur, W1T + (size_t)l * 256 * 128,
                                         b1 + l * 128, T128, Nn);
    // s = bf16(segmean(T))
    agg128_kernel<<<nagg, 256, 0, stream>>>(T128, rowptr, colv, invc, s128, Nn);
    // h = bf16(z + s @ W2 + b2)
    gemm_big64<0, 1, 0><<<mb64, 256, 0, stream>>>(s128, W2T + (size_t)l * 128 * 256,
                                                  b2 + l * 256, zcur, hbuf, nullptr,
                                                  nullptr, Nn, 128);
    // O = bf16(relu(h @ U1 + c1))
    gemm_big64<1, 0, 0><<<mb64, 256, 0, stream>>>(hbuf, U1T + (size_t)l * 256 * 256,
                                                  c1 + l * 256, nullptr, Obuf, nullptr,
                                                  nullptr, Nn, 256);
    // fold if all slots full
    if (pend == G) flush();
    // z' = bf16(LN(O @ U2 + c2)*g + b)
    ushort* znext = zbase + (size_t)pend * ZS;
    gemm_big64<0, 0, 1><<<mb64, 256, 0, stream>>>(Obuf, U2T + (size_t)l * 256 * 256,
                                                  c2 + l * 256, nullptr, znext,
                                                  ln_g + l * 256, ln_b + l * 256, Nn, 256);
    zcur = znext;
    pend++;
  }
  flush();
}

// Round 15
// 1242.672 us; speedup vs baseline: 1.0243x; 1.0038x over previous
//
#include <hip/hip_runtime.h>
#include <stdint.h>

typedef __attribute__((ext_vector_type(4))) float f32x4;
typedef __attribute__((ext_vector_type(8))) short bf16x8;

#define HIDC 256
#define MSGC 128
#define NLAYER 10

__device__ __forceinline__ ushort f2bf(float f) {
  union { float f; uint32_t u; } a; a.f = f;
  uint32_t u = a.u;
  return (ushort)((u + 0x7fffu + ((u >> 16) & 1u)) >> 16);
}
__device__ __forceinline__ float bf2f(ushort h) {
  union { float f; uint32_t u; } a; a.u = ((uint32_t)h) << 16;
  return a.f;
}

// async global->LDS, 16B per lane; dst is wave-uniform base (lane*16 added by HW)
__device__ __forceinline__ void gll16(const void* g, void* l) {
  __builtin_amdgcn_global_load_lds(
      (const __attribute__((address_space(1))) void*)g,
      (__attribute__((address_space(3))) void*)l, 16, 0, 0);
}

// ---------------------------------------------------------------------------
// W1 GEMM: A bf16 [M x 256], B bf16 [128 x 256](T), C bf16 [M x 128].
// Tile 64x128, 4 waves, BK=64, RELU fused. 24 KB LDS -> 6 blocks/CU.
// ---------------------------------------------------------------------------
__global__ __launch_bounds__(256, 6) void gemm_w1_64(
    const ushort* __restrict__ A, const ushort* __restrict__ B,
    const float* __restrict__ bias, ushort* __restrict__ C, int M) {
  __shared__ ushort lA[64 * 64];
  __shared__ ushort lB[128 * 64];
  const int tid = threadIdx.x;
  const int m0 = blockIdx.x * 64;
  const int lane = tid & 63;
  const int w = tid >> 6;
  const int wm = (w >> 1) * 32;  // 0,32
  const int wn = (w & 1) * 64;   // 0,64
  const int rr = tid >> 3;       // 0..31
  const int cc = tid & 7;        // 0..7
  const int ccs = cc ^ (rr & 7);
  const bool full = (m0 + 64 <= M);
  f32x4 acc[2][4] = {};

#pragma unroll
  for (int s = 0; s < 4; ++s) {  // K = 256
    const int k0 = s * 64;
    if (full) {
#pragma unroll
      for (int p = 0; p < 2; ++p) {
        const int row = p * 32 + rr;
        gll16(A + (size_t)(m0 + row) * 256 + k0 + ccs * 8,
              lA + (size_t)(p * 32 + w * 8) * 64);
      }
    } else {
#pragma unroll
      for (int p = 0; p < 2; ++p) {
        const int row = p * 32 + rr;
        const int gm = m0 + row;
        bf16x8 av = {0, 0, 0, 0, 0, 0, 0, 0};
        if (gm < M) av = *(const bf16x8*)(A + (size_t)gm * 256 + k0 + cc * 8);
        const uint32_t off = (uint32_t)((row * 128 + cc * 16) ^ ((row & 7) << 4));
        *(bf16x8*)((char*)lA + off) = av;
      }
    }
#pragma unroll
    for (int p = 0; p < 4; ++p) {
      const int row = p * 32 + rr;
      gll16(B + (size_t)row * 256 + k0 + ccs * 8,
            lB + (size_t)(p * 32 + w * 8) * 64);
    }
    __syncthreads();
#pragma unroll
    for (int kk = 0; kk < 2; ++kk) {
      bf16x8 ah[2];
#pragma unroll
      for (int i = 0; i < 2; ++i) {
        const int arow = wm + i * 16 + (lane & 15);
        const uint32_t ao =
            (uint32_t)((arow * 128 + kk * 64 + ((lane >> 4) * 16)) ^ ((arow & 7) << 4));
        ah[i] = *(const bf16x8*)((const char*)lA + ao);
      }
#pragma unroll
      for (int j = 0; j < 4; ++j) {
        const int brow = wn + j * 16 + (lane & 15);
        const uint32_t bo =
            (uint32_t)((brow * 128 + kk * 64 + ((lane >> 4) * 16)) ^ ((brow & 7) << 4));
        const bf16x8 bv = *(const bf16x8*)((const char*)lB + bo);
#pragma unroll
        for (int i = 0; i < 2; ++i)
          acc[i][j] = __builtin_amdgcn_mfma_f32_16x16x32_bf16(ah[i], bv, acc[i][j], 0, 0, 0);
      }
    }
    __syncthreads();
  }
  float bi[4];
#pragma unroll
  for (int j = 0; j < 4; ++j) bi[j] = bias[wn + j * 16 + (lane & 15)];
#pragma unroll
  for (int i = 0; i < 2; ++i) {
    const int gm0 = m0 + wm + i * 16 + ((lane >> 4) << 2);
#pragma unroll
    for (int r = 0; r < 4; ++r) {
      const int gm = gm0 + r;
      if (gm < M) {
        const size_t base = (size_t)gm * 128 + wn + (lane & 15);
#pragma unroll
        for (int j = 0; j < 4; ++j)
          C[base + j * 16] = f2bf(fmaxf(acc[i][j][r] + bi[j], 0.f));
      }
    }
  }
}

// ---------------------------------------------------------------------------
// Big GEMM 64-row, double-buffered: BK=32, 2-phase prefetch, 40 KB LDS
// (sstat overlaid) -> 4 blocks/CU. setprio around MFMA cluster.
// LN=0: C = bf16(act(A@B^T + bias [+Z]));  LN=1: C = bf16(LN(..)*g+b_)
// ---------------------------------------------------------------------------
template <int RELU, int ADDZ, int LN>
__global__ __launch_bounds__(256, 4) void gemm_big64(
    const ushort* __restrict__ A, const ushort* __restrict__ B,
    const float* __restrict__ bias, const ushort* __restrict__ Z,
    ushort* __restrict__ C, const float* __restrict__ g,
    const float* __restrict__ b_, int M, int K) {
  __shared__ char smem[40960];  // [0,8K) lA[2] | [8K,40K) lB[2]
  ushort* lAbase = (ushort*)smem;
  ushort* lBbase = (ushort*)(smem + 8192);
  float* sstat = (float*)smem;  // overlay [2][4][64], epilogue only
  const int tid = threadIdx.x;
  const int m0 = blockIdx.x * 64;
  const int lane = tid & 63;
  const int w = tid >> 6;
  const int wn = w * 64;
  const int srow = tid >> 2;
  const int scc = tid & 3;
  const bool full = (m0 + 64 <= M);
  f32x4 acc[4][4] = {};
  const int nsteps = K >> 5;

  auto stage = [&](int s, int buf) {
    const int k0 = s * 32;
    ushort* lA = lAbase + buf * 64 * 32;
    ushort* lB = lBbase + buf * 256 * 32;
    if (full) {
      const int ccs = scc ^ ((srow >> 1) & 3);
      gll16(A + (size_t)(m0 + srow) * K + k0 + ccs * 8, lA + (w * 16) * 32);
    } else {
      const int gm = m0 + srow;
      bf16x8 av = {0, 0, 0, 0, 0, 0, 0, 0};
      if (gm < M) av = *(const bf16x8*)(A + (size_t)gm * K + k0 + scc * 8);
      const uint32_t off = (uint32_t)((srow * 64 + scc * 16) ^ ((srow & 6) << 3));
      *(bf16x8*)((char*)lA + off) = av;
    }
#pragma unroll
    for (int p = 0; p < 4; ++p) {
      const int row = p * 64 + srow;
      const int ccs = scc ^ ((row >> 1) & 3);
      gll16(B + (size_t)row * K + k0 + ccs * 8, lB + (p * 64 + w * 16) * 32);
    }
  };

  int cur = 0;
  stage(0, 0);
  for (int s = 0; s < nsteps; ++s) {
    __syncthreads();
    if (s + 1 < nsteps) stage(s + 1, cur ^ 1);
    const ushort* lA = lAbase + cur * 64 * 32;
    const ushort* lB = lBbase + cur * 256 * 32;
    bf16x8 ah[4];
#pragma unroll
    for (int i = 0; i < 4; ++i) {
      const int arow = i * 16 + (lane & 15);
      const uint32_t ao =
          (uint32_t)((arow * 64 + ((lane >> 4) * 16)) ^ ((arow & 6) << 3));
      ah[i] = *(const bf16x8*)((const char*)lA + ao);
    }
    __builtin_amdgcn_s_setprio(1);
#pragma unroll
    for (int j = 0; j < 4; ++j) {
      const int brow = wn + j * 16 + (lane & 15);
      const uint32_t bo =
          (uint32_t)((brow * 64 + ((lane >> 4) * 16)) ^ ((brow & 6) << 3));
      const bf16x8 bv = *(const bf16x8*)((const char*)lB + bo);
#pragma unroll
      for (int i = 0; i < 4; ++i)
        acc[i][j] = __builtin_amdgcn_mfma_f32_16x16x32_bf16(ah[i], bv, acc[i][j], 0, 0, 0);
    }
    __builtin_amdgcn_s_setprio(0);
    cur ^= 1;
  }
  __syncthreads();

  float bi[4];
#pragma unroll
  for (int j = 0; j < 4; ++j) bi[j] = bias[wn + j * 16 + (lane & 15)];

  if (LN) {
    float gv[4], bv[4];
#pragma unroll
    for (int j = 0; j < 4; ++j) {
      gv[j] = g[wn + j * 16 + (lane & 15)];
      bv[j] = b_[wn + j * 16 + (lane & 15)];
    }
#pragma unroll
    for (int i = 0; i < 4; ++i) {
#pragma unroll
      for (int r = 0; r < 4; ++r) {
        float s1 = 0.f, s2 = 0.f;
#pragma unroll
        for (int j = 0; j < 4; ++j) {
          float v = acc[i][j][r] + bi[j];
          acc[i][j][r] = v;
          s1 += v;
          s2 += v * v;
        }
#pragma unroll
        for (int d = 1; d < 16; d <<= 1) {
          s1 += __shfl_xor(s1, d);
          s2 += __shfl_xor(s2, d);
        }
        if ((lane & 15) == 0) {
          const int rl = i * 16 + ((lane >> 4) << 2) + r;
          sstat[(0 * 4 + w) * 64 + rl] = s1;
          sstat[(1 * 4 + w) * 64 + rl] = s2;
        }
      }
    }
    __syncthreads();
#pragma unroll
    for (int i = 0; i < 4; ++i) {
#pragma unroll
      for (int r = 0; r < 4; ++r) {
        const int rl = i * 16 + ((lane >> 4) << 2) + r;
        const float s1 = sstat[0 * 256 + 0 * 64 + rl] + sstat[0 * 256 + 1 * 64 + rl] +
                         sstat[0 * 256 + 2 * 64 + rl] + sstat[0 * 256 + 3 * 64 + rl];
        const float s2 = sstat[1 * 256 + 0 * 64 + rl] + sstat[1 * 256 + 1 * 64 + rl] +
                         sstat[1 * 256 + 2 * 64 + rl] + sstat[1 * 256 + 3 * 64 + rl];
        const float mu = s1 * (1.f / 256.f);
        const float var = s2 * (1.f / 256.f) - mu * mu;
        const float rs = rsqrtf(var + 1e-5f);
        const int gm = m0 + rl;
        if (gm < M) {
          const size_t base = (size_t)gm * 256 + wn + (lane & 15);
#pragma unroll
          for (int j = 0; j < 4; ++j)
            C[base + j * 16] = f2bf((acc[i][j][r] - mu) * rs * gv[j] + bv[j]);
        }
      }
    }
  } else {
#pragma unroll
    for (int i = 0; i < 4; ++i) {
      const int gm0 = m0 + i * 16 + ((lane >> 4) << 2);
#pragma unroll
      for (int r = 0; r < 4; ++r) {
        const int gm = gm0 + r;
        if (gm < M) {
          const size_t base = (size_t)gm * 256 + wn + (lane & 15);
#pragma unroll
          for (int j = 0; j < 4; ++j) {
            float v = acc[i][j][r] + bi[j];
            if (ADDZ) v += bf2f(Z[base + j * 16]);
            if (RELU) v = fmaxf(v, 0.f);
            C[base + j * 16] = f2bf(v);
          }
        }
      }
    }
  }
}

// ---------------------------------------------------------------------------
// Fold (grid-stride): outp (+)= sum_{k<P} betas[l0+k]*bf2f(zbase[k][i]).
// ---------------------------------------------------------------------------
template <int WRITE>
__global__ __launch_bounds__(256) void fold_kernel(
    const ushort* __restrict__ zbase, size_t ZS, const float* __restrict__ betas,
    int l0, int P, float* __restrict__ outp, int total8) {
  for (int i = blockIdx.x * 256 + threadIdx.x; i < total8; i += gridDim.x * 256) {
    float a[8] = {};
    for (int k = 0; k < P; ++k) {
      const float bl = betas[l0 + k];
      const uint4 u = ((const uint4*)(zbase + k * ZS))[i];
      const uint32_t ww[4] = {u.x, u.y, u.z, u.w};
#pragma unroll
      for (int q = 0; q < 4; ++q) {
        union { uint32_t u; float f; } lo, hi;
        lo.u = ww[q] << 16;
        hi.u = ww[q] & 0xffff0000u;
        a[2 * q] += bl * lo.f;
        a[2 * q + 1] += bl * hi.f;
      }
    }
    f32x4 o0 = {a[0], a[1], a[2], a[3]};
    f32x4 o1 = {a[4], a[5], a[6], a[7]};
    if (WRITE) {
      ((f32x4*)outp)[(size_t)i * 2] = o0;
      ((f32x4*)outp)[(size_t)i * 2 + 1] = o1;
    } else {
      f32x4 p0 = ((f32x4*)outp)[(size_t)i * 2];
      f32x4 p1 = ((f32x4*)outp)[(size_t)i * 2 + 1];
      ((f32x4*)outp)[(size_t)i * 2] = p0 + o0;
      ((f32x4*)outp)[(size_t)i * 2 + 1] = p1 + o1;
    }
  }
}

// ---------------------------------------------------------------------------
// CSR build: count stores per-edge slot; fill is atomic-free scatter.
// ---------------------------------------------------------------------------
__global__ void count_kernel(const int* __restrict__ dstv, int* __restrict__ deg,
                             int* __restrict__ eoff, int E) {
  int i = blockIdx.x * 256 + threadIdx.x;
  if (i < E) eoff[i] = atomicAdd(&deg[dstv[i]], 1);
}

__global__ void scanA_kernel(const int* __restrict__ deg, int* __restrict__ excl,
                             int* __restrict__ bsum, int n) {
  __shared__ int sm[256];
  const int i = blockIdx.x * 256 + threadIdx.x;
  const int v = (i < n) ? deg[i] : 0;
  sm[threadIdx.x] = v;
  __syncthreads();
  for (int off = 1; off < 256; off <<= 1) {
    int t = (threadIdx.x >= off) ? sm[threadIdx.x - off] : 0;
    __syncthreads();
    sm[threadIdx.x] += t;
    __syncthreads();
  }
  if (i < n) excl[i] = sm[threadIdx.x] - v;
  if (threadIdx.x == 255) bsum[blockIdx.x] = sm[255];
}

__global__ void scanB_kernel(const int* __restrict__ bsum, int* __restrict__ boff, int nb) {
  __shared__ int sm[256];
  const int v = (threadIdx.x < nb) ? bsum[threadIdx.x] : 0;
  sm[threadIdx.x] = v;
  __syncthreads();
  for (int off = 1; off < 256; off <<= 1) {
    int t = (threadIdx.x >= off) ? sm[threadIdx.x - off] : 0;
    __syncthreads();
    sm[threadIdx.x] += t;
    __syncthreads();
  }
  if (threadIdx.x < nb) boff[threadIdx.x] = sm[threadIdx.x] - v;
}

__global__ void scanC_kernel(const int* __restrict__ deg, const int* __restrict__ excl,
                             const int* __restrict__ boff, int* __restrict__ rowptr,
                             float* __restrict__ invc, int n, int E) {
  const int i = blockIdx.x * 256 + threadIdx.x;
  if (i < n) {
    rowptr[i] = excl[i] + boff[blockIdx.x];
    invc[i] = 1.0f / (float)(deg[i] + 1);
  }
  if (i == 0) rowptr[n] = E;
}

__global__ void fill_kernel(const int* __restrict__ srcv, const int* __restrict__ dstv,
                            const int* __restrict__ rowptr, const int* __restrict__ eoff,
                            int* __restrict__ colv, int E) {
  int i = blockIdx.x * 256 + threadIdx.x;
  if (i < E) colv[rowptr[dstv[i]] + eoff[i]] = srcv[i];
}

// ---------------------------------------------------------------------------
// 128-d aggregation, quarter-wave (16 lanes x 16B) per node, x4 unroll.
// ---------------------------------------------------------------------------
__global__ __launch_bounds__(256) void agg128_kernel(
    const ushort* __restrict__ T, const int* __restrict__ rowptr,
    const int* __restrict__ colv, const float* __restrict__ invc,
    ushort* __restrict__ sout, int n) {
  const int node = blockIdx.x * 16 + (threadIdx.x >> 4);
  if (node >= n) return;
  const int q = threadIdx.x & 15;
  const uint4* Tv = (const uint4*)T;
  float a[8] = {}, b[8] = {}, c[8] = {}, d[8] = {};
  auto addu = [](float* acc, uint4 u) {
    const uint32_t ww[4] = {u.x, u.y, u.z, u.w};
#pragma unroll
    for (int k = 0; k < 4; ++k) {
      union { uint32_t u; float f; } lo, hi;
      lo.u = ww[k] << 16;
      hi.u = ww[k] & 0xffff0000u;
      acc[2 * k] += lo.f;
      acc[2 * k + 1] += hi.f;
    }
  };
  addu(a, Tv[(size_t)node * 16 + q]);
  const int s = rowptr[node];
  const int e = rowptr[node + 1];
  int i = s;
  for (; i + 3 < e; i += 4) {
    const uint4 u0 = Tv[(size_t)colv[i] * 16 + q];
    const uint4 u1 = Tv[(size_t)colv[i + 1] * 16 + q];
    const uint4 u2 = Tv[(size_t)colv[i + 2] * 16 + q];
    const uint4 u3 = Tv[(size_t)colv[i + 3] * 16 + q];
    addu(a, u0);
    addu(b, u1);
    addu(c, u2);
    addu(d, u3);
  }
  for (; i < e; ++i) addu(a, Tv[(size_t)colv[i] * 16 + q]);
  const float ic = invc[node];
  uint4 o;
  uint32_t* ow = (uint32_t*)&o;
#pragma unroll
  for (int k = 0; k < 4; ++k) {
    const float r0 = (a[2 * k] + b[2 * k] + c[2 * k] + d[2 * k]) * ic;
    const float r1 = (a[2 * k + 1] + b[2 * k + 1] + c[2 * k + 1] + d[2 * k + 1]) * ic;
    ow[k] = (uint32_t)f2bf(r0) | ((uint32_t)f2bf(r1) << 16);
  }
  ((uint4*)sout)[(size_t)node * 16 + q] = o;
}

__global__ void beta_kernel(const float* __restrict__ beta, float* __restrict__ betas) {
  if (threadIdx.x == 0) {
    float mx = beta[0];
    for (int i = 1; i < NLAYER + 1; ++i) mx = fmaxf(mx, beta[i]);
    float e[NLAYER + 1];
    float s = 0.f;
    for (int i = 0; i < NLAYER + 1; ++i) {
      e[i] = expf(beta[i] - mx);
      s += e[i];
    }
    const float inv = 1.f / s;
    for (int i = 0; i < NLAYER + 1; ++i) betas[i] = e[i] * inv;
  }
}

// W [L][K][N] f32 -> Wt [L][N][K] bf16 via 32x32 LDS tile
__global__ void wconv_t(const float* __restrict__ W, ushort* __restrict__ Wt,
                        int K, int Nn) {
  __shared__ float t[32][33];
  const size_t mat = (size_t)blockIdx.z * K * Nn;
  const int kk0 = blockIdx.x * 32;
  const int nn0 = blockIdx.y * 32;
  const int tx = threadIdx.x & 31;
  const int ty = threadIdx.x >> 5;  // 0..7
#pragma unroll
  for (int i = 0; i < 4; ++i)
    t[ty * 4 + i][tx] = W[mat + (size_t)(kk0 + ty * 4 + i) * Nn + nn0 + tx];
  __syncthreads();
#pragma unroll
  for (int i = 0; i < 4; ++i)
    Wt[mat + (size_t)(nn0 + ty * 4 + i) * K + kk0 + tx] = f2bf(t[tx][ty * 4 + i]);
}

// Win GEMM (z0): A f32 [M x 128] (cast to bf16 during staging),
// B bf16 [256 x 128], C bf16 [M x 256]. Tile 128x256, 8 waves, BK=64.
__global__ __launch_bounds__(512, 4) void gemm_win(
    const float* __restrict__ A, const ushort* __restrict__ B,
    const float* __restrict__ bias, ushort* __restrict__ C, int M) {
  __shared__ ushort lA[128 * 64];
  __shared__ ushort lB[256 * 64];
  const int tid = threadIdx.x;
  const int m0 = blockIdx.x * 128;
  const int lane = tid & 63;
  const int w = tid >> 6;
  const int wm = (w >> 2) * 64;
  const int wn = (w & 3) * 64;
  const int rr = tid >> 3;
  const int cc = tid & 7;
  const int ccs = cc ^ (rr & 7);
  f32x4 acc[4][4] = {};
  const int K = 128;

#pragma unroll
  for (int s = 0; s < 2; ++s) {
    const int k0 = s * 64;
    // A: f32 -> bf16 convert during staging (guarded VGPR path)
#pragma unroll
    for (int p = 0; p < 2; ++p) {
      const int row = p * 64 + rr;
      const int gm = m0 + row;
      f32x4 va = {0.f, 0.f, 0.f, 0.f}, vb = {0.f, 0.f, 0.f, 0.f};
      if (gm < M) {
        const float* ga = A + (size_t)gm * K + k0 + cc * 8;
        va = *(const f32x4*)ga;
        vb = *(const f32x4*)(ga + 4);
      }
      bf16x8 hv;
#pragma unroll
      for (int e = 0; e < 4; ++e) {
        hv[e] = (short)f2bf(va[e]);
        hv[e + 4] = (short)f2bf(vb[e]);
      }
      const uint32_t off = (uint32_t)((row * 128 + cc * 16) ^ ((row & 7) << 4));
      *(bf16x8*)((char*)lA + off) = hv;
    }
#pragma unroll
    for (int p = 0; p < 4; ++p) {
      const int row = p * 64 + rr;
      gll16(B + (size_t)row * K + k0 + ccs * 8,
            lB + (size_t)(p * 64 + w * 8) * 64);
    }
    __syncthreads();
#pragma unroll
    for (int kk = 0; kk < 2; ++kk) {
      bf16x8 ah[4];
#pragma unroll
      for (int i = 0; i < 4; ++i) {
        const int arow = wm + i * 16 + (lane & 15);
        const uint32_t ao =
            (uint32_t)((arow * 128 + kk * 64 + ((lane >> 4) * 16)) ^ ((arow & 7) << 4));
        ah[i] = *(const bf16x8*)((const char*)lA + ao);
      }
#pragma unroll
      for (int j = 0; j < 4; ++j) {
        const int brow = wn + j * 16 + (lane & 15);
        const uint32_t bo =
            (uint32_t)((brow * 128 + kk * 64 + ((lane >> 4) * 16)) ^ ((brow & 7) << 4));
        const bf16x8 bv = *(const bf16x8*)((const char*)lB + bo);
#pragma unroll
        for (int i = 0; i < 4; ++i)
          acc[i][j] = __builtin_amdgcn_mfma_f32_16x16x32_bf16(ah[i], bv, acc[i][j], 0, 0, 0);
      }
    }
    __syncthreads();
  }
  float bi[4];
#pragma unroll
  for (int j = 0; j < 4; ++j) bi[j] = bias[wn + j * 16 + (lane & 15)];
#pragma unroll
  for (int i = 0; i < 4; ++i) {
    const int gm0 = m0 + wm + i * 16 + ((lane >> 4) << 2);
#pragma unroll
    for (int r = 0; r < 4; ++r) {
      const int gm = gm0 + r;
      if (gm < M) {
        const size_t base = (size_t)gm * 256 + wn + (lane & 15);
#pragma unroll
        for (int j = 0; j < 4; ++j)
          C[base + j * 16] = f2bf(acc[i][j][r] + bi[j]);
      }
    }
  }
}

// ---------------------------------------------------------------------------
extern "C" void kernel_launch(void* const* d_in, const int* in_sizes, int n_in,
                              void* d_out, int out_size, void* d_ws, size_t ws_size,
                              hipStream_t stream) {
  const float* x = (const float*)d_in[0];
  const int* eidx = (const int*)d_in[1];
  const float* Win = (const float*)d_in[2];
  const float* bin_ = (const float*)d_in[3];
  const float* W1 = (const float*)d_in[4];
  const float* b1 = (const float*)d_in[5];
  const float* W2 = (const float*)d_in[6];
  const float* b2 = (const float*)d_in[7];
  const float* U1 = (const float*)d_in[8];
  const float* c1 = (const float*)d_in[9];
  const float* U2 = (const float*)d_in[10];
  const float* c2 = (const float*)d_in[11];
  const float* ln_g = (const float*)d_in[12];
  const float* ln_b = (const float*)d_in[13];
  const float* beta = (const float*)d_in[14];
  float* outp = (float*)d_out;

  const int Nn = in_sizes[0] / 128;  // 50000
  const int E = in_sizes[1] / 2;     // 800000
  const int* srcv = eidx;
  const int* dstv = eidx + E;

  char* p = (char*)d_ws;
  auto alloc = [&](size_t bytes) {
    char* r = p;
    p += (bytes + 255) & ~(size_t)255;
    return r;
  };
  ushort* hbuf = (ushort*)alloc((size_t)Nn * HIDC * 2);  // h bf16
  ushort* TSO = (ushort*)alloc((size_t)Nn * HIDC * 2);   // T | s, later O
  ushort* WinT = (ushort*)alloc(128 * 256 * 2);
  ushort* W1T = (ushort*)alloc((size_t)NLAYER * 256 * 128 * 2);
  ushort* W2T = (ushort*)alloc((size_t)NLAYER * 128 * 256 * 2);
  ushort* U1T = (ushort*)alloc((size_t)NLAYER * 256 * 256 * 2);
  ushort* U2T = (ushort*)alloc((size_t)NLAYER * 256 * 256 * 2);
  int* deg = (int*)alloc((size_t)Nn * 4);
  int* rowptr = (int*)alloc((size_t)(Nn + 1) * 4);
  float* invc = (float*)alloc((size_t)Nn * 4);
  int* colv = (int*)alloc((size_t)E * 4);
  int* eoff = (int*)alloc((size_t)E * 4);
  int* excl = (int*)alloc((size_t)Nn * 4);
  int* bsum = (int*)alloc(256 * 4);
  int* boff = (int*)alloc(256 * 4);
  float* betas = (float*)alloc(64);

  // z-history slots: as many as fit (G in [2, 11])
  const size_t ZS = (size_t)Nn * HIDC;
  const size_t slotB = ZS * 2;
  const size_t used = (size_t)(p - (char*)d_ws);
  int G = 2;
  if (ws_size > used + 4096) {
    size_t fit = (ws_size - used - 4096) / (slotB + 256);
    G = (int)(fit < 2 ? 2 : (fit > NLAYER + 1 ? NLAYER + 1 : fit));
  }
  ushort* zbase = (ushort*)alloc((size_t)G * slotB);

  ushort* T128 = TSO;
  ushort* s128 = TSO + (size_t)Nn * MSGC;
  ushort* Obuf = TSO;  // reuses T|s after both consumed

  const int nscan = (Nn + 255) / 256;
  const int mb128 = (Nn + 127) / 128;
  const int mb64 = (Nn + 63) / 64;
  const int nagg = (Nn + 15) / 16;
  const int total8 = (Nn * HIDC) / 8;
  const int foldgrid = 2048;

  hipMemsetAsync(deg, 0, (size_t)Nn * 4, stream);
  count_kernel<<<(E + 255) / 256, 256, 0, stream>>>(dstv, deg, eoff, E);
  scanA_kernel<<<nscan, 256, 0, stream>>>(deg, excl, bsum, Nn);
  scanB_kernel<<<1, 256, 0, stream>>>(bsum, boff, nscan);
  scanC_kernel<<<nscan, 256, 0, stream>>>(deg, excl, boff, rowptr, invc, Nn, E);
  fill_kernel<<<(E + 255) / 256, 256, 0, stream>>>(srcv, dstv, rowptr, eoff, colv, E);
  beta_kernel<<<1, 64, 0, stream>>>(beta, betas);
  wconv_t<<<dim3(4, 8, 1), 256, 0, stream>>>(Win, WinT, 128, 256);
  wconv_t<<<dim3(8, 4, NLAYER), 256, 0, stream>>>(W1, W1T, 256, 128);
  wconv_t<<<dim3(4, 8, NLAYER), 256, 0, stream>>>(W2, W2T, 128, 256);
  wconv_t<<<dim3(8, 8, NLAYER), 256, 0, stream>>>(U1, U1T, 256, 256);
  wconv_t<<<dim3(8, 8, NLAYER), 256, 0, stream>>>(U2, U2T, 256, 256);

  // fold bookkeeping
  int pend = 0, l0 = 0;
  bool first = true;
  auto flush = [&]() {
    if (pend > 0) {
      if (first)
        fold_kernel<1><<<foldgrid, 256, 0, stream>>>(zbase, ZS, betas, l0, pend, outp,
                                                     total8);
      else
        fold_kernel<0><<<foldgrid, 256, 0, stream>>>(zbase, ZS, betas, l0, pend, outp,
                                                     total8);
      first = false;
      l0 += pend;
      pend = 0;
    }
  };

  // z0 = x @ Win + bin -> slot 0 (xcast fused into staging)
  ushort* zcur = zbase;
  gemm_win<<<mb128, 512, 0, stream>>>(x, WinT, bin_, zcur, Nn);
  pend = 1;

  for (int l = 0; l < NLAYER; ++l) {
    // T = bf16(relu(z @ W1 + b1))
    gemm_w1_64<<<mb64, 256, 0, stream>>>(zcur, W1T + (size_t)l * 256 * 128,
                                         b1 + l * 128, T128, Nn);
    // s = bf16(segmean(T))
    agg128_kernel<<<nagg, 256, 0, stream>>>(T128, rowptr, colv, invc, s128, Nn);
    // h = bf16(z + s @ W2 + b2)
    gemm_big64<0, 1, 0><<<mb64, 256, 0, stream>>>(s128, W2T + (size_t)l * 128 * 256,
                                                  b2 + l * 256, zcur, hbuf, nullptr,
                                                  nullptr, Nn, 128);
    // O = bf16(relu(h @ U1 + c1))
    gemm_big64<1, 0, 0><<<mb64, 256, 0, stream>>>(hbuf, U1T + (size_t)l * 256 * 256,
                                                  c1 + l * 256, nullptr, Obuf, nullptr,
                                                  nullptr, Nn, 256);
    // fold if all slots full
    if (pend == G) flush();
    // z' = bf16(LN(O @ U2 + c2)*g + b)
    ushort* znext = zbase + (size_t)pend * ZS;
    gemm_big64<0, 0, 1><<<mb64, 256, 0, stream>>>(Obuf, U2T + (size_t)l * 256 * 256,
                                                  c2 + l * 256, nullptr, znext,
                                                  ln_g + l * 256, ln_b + l * 256, Nn, 256);
    zcur = znext;
    pend++;
  }
  flush();
}

// Round 17
// 1230.826 us; speedup vs baseline: 1.0342x; 1.0096x over previous
//
#include <hip/hip_runtime.h>
#include <stdint.h>

typedef __attribute__((ext_vector_type(4))) float f32x4;
typedef __attribute__((ext_vector_type(8))) short bf16x8;
typedef __attribute__((ext_vector_type(4))) uint32_t u32x4;

#define HIDC 256
#define MSGC 128
#define NLAYER 10

__device__ __forceinline__ ushort f2bf(float f) {
  union { float f; uint32_t u; } a; a.f = f;
  uint32_t u = a.u;
  return (ushort)((u + 0x7fffu + ((u >> 16) & 1u)) >> 16);
}
__device__ __forceinline__ float bf2f(ushort h) {
  union { float f; uint32_t u; } a; a.u = ((uint32_t)h) << 16;
  return a.f;
}

// async global->LDS, 16B per lane; dst is wave-uniform base (lane*16 added by HW)
__device__ __forceinline__ void gll16(const void* g, void* l) {
  __builtin_amdgcn_global_load_lds(
      (const __attribute__((address_space(1))) void*)g,
      (__attribute__((address_space(3))) void*)l, 16, 0, 0);
}

// ---------------------------------------------------------------------------
// W1 GEMM: A bf16 [M x 256], B bf16 [128 x 256](T), C bf16 [M x 128].
// Tile 64x128, 4 waves, BK=64, RELU fused. 24 KB LDS -> 6 blocks/CU.
// ---------------------------------------------------------------------------
__global__ __launch_bounds__(256, 6) void gemm_w1_64(
    const ushort* __restrict__ A, const ushort* __restrict__ B,
    const float* __restrict__ bias, ushort* __restrict__ C, int M) {
  __shared__ ushort lA[64 * 64];
  __shared__ ushort lB[128 * 64];
  const int tid = threadIdx.x;
  const int m0 = blockIdx.x * 64;
  const int lane = tid & 63;
  const int w = tid >> 6;
  const int wm = (w >> 1) * 32;  // 0,32
  const int wn = (w & 1) * 64;   // 0,64
  const int rr = tid >> 3;       // 0..31
  const int cc = tid & 7;        // 0..7
  const int ccs = cc ^ (rr & 7);
  const bool full = (m0 + 64 <= M);
  f32x4 acc[2][4] = {};

#pragma unroll
  for (int s = 0; s < 4; ++s) {  // K = 256
    const int k0 = s * 64;
    if (full) {
#pragma unroll
      for (int p = 0; p < 2; ++p) {
        const int row = p * 32 + rr;
        gll16(A + (size_t)(m0 + row) * 256 + k0 + ccs * 8,
              lA + (size_t)(p * 32 + w * 8) * 64);
      }
    } else {
#pragma unroll
      for (int p = 0; p < 2; ++p) {
        const int row = p * 32 + rr;
        const int gm = m0 + row;
        bf16x8 av = {0, 0, 0, 0, 0, 0, 0, 0};
        if (gm < M) av = *(const bf16x8*)(A + (size_t)gm * 256 + k0 + cc * 8);
        const uint32_t off = (uint32_t)((row * 128 + cc * 16) ^ ((row & 7) << 4));
        *(bf16x8*)((char*)lA + off) = av;
      }
    }
#pragma unroll
    for (int p = 0; p < 4; ++p) {
      const int row = p * 32 + rr;
      gll16(B + (size_t)row * 256 + k0 + ccs * 8,
            lB + (size_t)(p * 32 + w * 8) * 64);
    }
    __syncthreads();
#pragma unroll
    for (int kk = 0; kk < 2; ++kk) {
      bf16x8 ah[2];
#pragma unroll
      for (int i = 0; i < 2; ++i) {
        const int arow = wm + i * 16 + (lane & 15);
        const uint32_t ao =
            (uint32_t)((arow * 128 + kk * 64 + ((lane >> 4) * 16)) ^ ((arow & 7) << 4));
        ah[i] = *(const bf16x8*)((const char*)lA + ao);
      }
#pragma unroll
      for (int j = 0; j < 4; ++j) {
        const int brow = wn + j * 16 + (lane & 15);
        const uint32_t bo =
            (uint32_t)((brow * 128 + kk * 64 + ((lane >> 4) * 16)) ^ ((brow & 7) << 4));
        const bf16x8 bv = *(const bf16x8*)((const char*)lB + bo);
#pragma unroll
        for (int i = 0; i < 2; ++i)
          acc[i][j] = __builtin_amdgcn_mfma_f32_16x16x32_bf16(ah[i], bv, acc[i][j], 0, 0, 0);
      }
    }
    __syncthreads();
  }
  float bi[4];
#pragma unroll
  for (int j = 0; j < 4; ++j) bi[j] = bias[wn + j * 16 + (lane & 15)];
#pragma unroll
  for (int i = 0; i < 2; ++i) {
    const int gm0 = m0 + wm + i * 16 + ((lane >> 4) << 2);
#pragma unroll
    for (int r = 0; r < 4; ++r) {
      const int gm = gm0 + r;
      if (gm < M) {
        const size_t base = (size_t)gm * 128 + wn + (lane & 15);
#pragma unroll
        for (int j = 0; j < 4; ++j)
          C[base + j * 16] = f2bf(fmaxf(acc[i][j][r] + bi[j], 0.f));
      }
    }
  }
}

// ---------------------------------------------------------------------------
// Big GEMM 64-row, double-buffered: BK=32, 2-phase prefetch, 40 KB LDS
// (sstat overlaid) -> 4 blocks/CU. setprio around MFMA cluster.
// LN=0: C = bf16(act(A@B^T + bias [+Z]));  LN=1: C = bf16(LN(..)*g+b_)
// ---------------------------------------------------------------------------
template <int RELU, int ADDZ, int LN>
__global__ __launch_bounds__(256, 4) void gemm_big64(
    const ushort* __restrict__ A, const ushort* __restrict__ B,
    const float* __restrict__ bias, const ushort* __restrict__ Z,
    ushort* __restrict__ C, const float* __restrict__ g,
    const float* __restrict__ b_, int M, int K) {
  __shared__ char smem[40960];  // [0,8K) lA[2] | [8K,40K) lB[2]
  ushort* lAbase = (ushort*)smem;
  ushort* lBbase = (ushort*)(smem + 8192);
  float* sstat = (float*)smem;  // overlay [2][4][64], epilogue only
  const int tid = threadIdx.x;
  const int m0 = blockIdx.x * 64;
  const int lane = tid & 63;
  const int w = tid >> 6;
  const int wn = w * 64;
  const int srow = tid >> 2;
  const int scc = tid & 3;
  const bool full = (m0 + 64 <= M);
  f32x4 acc[4][4] = {};
  const int nsteps = K >> 5;

  auto stage = [&](int s, int buf) {
    const int k0 = s * 32;
    ushort* lA = lAbase + buf * 64 * 32;
    ushort* lB = lBbase + buf * 256 * 32;
    if (full) {
      const int ccs = scc ^ ((srow >> 1) & 3);
      gll16(A + (size_t)(m0 + srow) * K + k0 + ccs * 8, lA + (w * 16) * 32);
    } else {
      const int gm = m0 + srow;
      bf16x8 av = {0, 0, 0, 0, 0, 0, 0, 0};
      if (gm < M) av = *(const bf16x8*)(A + (size_t)gm * K + k0 + scc * 8);
      const uint32_t off = (uint32_t)((srow * 64 + scc * 16) ^ ((srow & 6) << 3));
      *(bf16x8*)((char*)lA + off) = av;
    }
#pragma unroll
    for (int p = 0; p < 4; ++p) {
      const int row = p * 64 + srow;
      const int ccs = scc ^ ((row >> 1) & 3);
      gll16(B + (size_t)row * K + k0 + ccs * 8, lB + (p * 64 + w * 16) * 32);
    }
  };

  int cur = 0;
  stage(0, 0);
  for (int s = 0; s < nsteps; ++s) {
    __syncthreads();
    if (s + 1 < nsteps) stage(s + 1, cur ^ 1);
    const ushort* lA = lAbase + cur * 64 * 32;
    const ushort* lB = lBbase + cur * 256 * 32;
    bf16x8 ah[4];
#pragma unroll
    for (int i = 0; i < 4; ++i) {
      const int arow = i * 16 + (lane & 15);
      const uint32_t ao =
          (uint32_t)((arow * 64 + ((lane >> 4) * 16)) ^ ((arow & 6) << 3));
      ah[i] = *(const bf16x8*)((const char*)lA + ao);
    }
    __builtin_amdgcn_s_setprio(1);
#pragma unroll
    for (int j = 0; j < 4; ++j) {
      const int brow = wn + j * 16 + (lane & 15);
      const uint32_t bo =
          (uint32_t)((brow * 64 + ((lane >> 4) * 16)) ^ ((brow & 6) << 3));
      const bf16x8 bv = *(const bf16x8*)((const char*)lB + bo);
#pragma unroll
      for (int i = 0; i < 4; ++i)
        acc[i][j] = __builtin_amdgcn_mfma_f32_16x16x32_bf16(ah[i], bv, acc[i][j], 0, 0, 0);
    }
    __builtin_amdgcn_s_setprio(0);
    cur ^= 1;
  }
  __syncthreads();

  float bi[4];
#pragma unroll
  for (int j = 0; j < 4; ++j) bi[j] = bias[wn + j * 16 + (lane & 15)];

  if (LN) {
    float gv[4], bv[4];
#pragma unroll
    for (int j = 0; j < 4; ++j) {
      gv[j] = g[wn + j * 16 + (lane & 15)];
      bv[j] = b_[wn + j * 16 + (lane & 15)];
    }
#pragma unroll
    for (int i = 0; i < 4; ++i) {
#pragma unroll
      for (int r = 0; r < 4; ++r) {
        float s1 = 0.f, s2 = 0.f;
#pragma unroll
        for (int j = 0; j < 4; ++j) {
          float v = acc[i][j][r] + bi[j];
          acc[i][j][r] = v;
          s1 += v;
          s2 += v * v;
        }
#pragma unroll
        for (int d = 1; d < 16; d <<= 1) {
          s1 += __shfl_xor(s1, d);
          s2 += __shfl_xor(s2, d);
        }
        if ((lane & 15) == 0) {
          const int rl = i * 16 + ((lane >> 4) << 2) + r;
          sstat[(0 * 4 + w) * 64 + rl] = s1;
          sstat[(1 * 4 + w) * 64 + rl] = s2;
        }
      }
    }
    __syncthreads();
#pragma unroll
    for (int i = 0; i < 4; ++i) {
#pragma unroll
      for (int r = 0; r < 4; ++r) {
        const int rl = i * 16 + ((lane >> 4) << 2) + r;
        const float s1 = sstat[0 * 256 + 0 * 64 + rl] + sstat[0 * 256 + 1 * 64 + rl] +
                         sstat[0 * 256 + 2 * 64 + rl] + sstat[0 * 256 + 3 * 64 + rl];
        const float s2 = sstat[1 * 256 + 0 * 64 + rl] + sstat[1 * 256 + 1 * 64 + rl] +
                         sstat[1 * 256 + 2 * 64 + rl] + sstat[1 * 256 + 3 * 64 + rl];
        const float mu = s1 * (1.f / 256.f);
        const float var = s2 * (1.f / 256.f) - mu * mu;
        const float rs = rsqrtf(var + 1e-5f);
        const int gm = m0 + rl;
        if (gm < M) {
          const size_t base = (size_t)gm * 256 + wn + (lane & 15);
#pragma unroll
          for (int j = 0; j < 4; ++j)
            C[base + j * 16] = f2bf((acc[i][j][r] - mu) * rs * gv[j] + bv[j]);
        }
      }
    }
  } else {
#pragma unroll
    for (int i = 0; i < 4; ++i) {
      const int gm0 = m0 + i * 16 + ((lane >> 4) << 2);
#pragma unroll
      for (int r = 0; r < 4; ++r) {
        const int gm = gm0 + r;
        if (gm < M) {
          const size_t base = (size_t)gm * 256 + wn + (lane & 15);
#pragma unroll
          for (int j = 0; j < 4; ++j) {
            float v = acc[i][j][r] + bi[j];
            if (ADDZ) v += bf2f(Z[base + j * 16]);
            if (RELU) v = fmaxf(v, 0.f);
            C[base + j * 16] = f2bf(v);
          }
        }
      }
    }
  }
}

// ---------------------------------------------------------------------------
// Fold (grid-stride, 16 elems/thread/iter, nontemporal slot loads):
// outp (+)= sum_{k<P} betas[l0+k]*bf2f(zbase[k][...]).
// ---------------------------------------------------------------------------
template <int WRITE>
__global__ __launch_bounds__(256) void fold_kernel(
    const ushort* __restrict__ zbase, size_t ZS, const float* __restrict__ betas,
    int l0, int P, float* __restrict__ outp, int total16) {
  for (int i = blockIdx.x * 256 + threadIdx.x; i < total16; i += gridDim.x * 256) {
    float a[16] = {};
    for (int k = 0; k < P; ++k) {
      const float bl = betas[l0 + k];
      const u32x4* src = (const u32x4*)(zbase + k * ZS) + (size_t)i * 2;
      const u32x4 u0 = __builtin_nontemporal_load(src);
      const u32x4 u1 = __builtin_nontemporal_load(src + 1);
      const uint32_t ww[8] = {u0.x, u0.y, u0.z, u0.w, u1.x, u1.y, u1.z, u1.w};
#pragma unroll
      for (int q = 0; q < 8; ++q) {
        union { uint32_t u; float f; } lo, hi;
        lo.u = ww[q] << 16;
        hi.u = ww[q] & 0xffff0000u;
        a[2 * q] += bl * lo.f;
        a[2 * q + 1] += bl * hi.f;
      }
    }
    f32x4 o[4];
#pragma unroll
    for (int q = 0; q < 4; ++q)
      o[q] = (f32x4){a[4 * q], a[4 * q + 1], a[4 * q + 2], a[4 * q + 3]};
    f32x4* dst = (f32x4*)outp + (size_t)i * 4;
    if (WRITE) {
#pragma unroll
      for (int q = 0; q < 4; ++q) dst[q] = o[q];
    } else {
#pragma unroll
      for (int q = 0; q < 4; ++q) {
        f32x4 pv = dst[q];
        dst[q] = pv + o[q];
      }
    }
  }
}

// ---------------------------------------------------------------------------
// CSR build: count stores per-edge slot; fill is atomic-free scatter.
// ---------------------------------------------------------------------------
__global__ void count_kernel(const int* __restrict__ dstv, int* __restrict__ deg,
                             int* __restrict__ eoff, int E) {
  int i = blockIdx.x * 256 + threadIdx.x;
  if (i < E) eoff[i] = atomicAdd(&deg[dstv[i]], 1);
}

__global__ void scanA_kernel(const int* __restrict__ deg, int* __restrict__ excl,
                             int* __restrict__ bsum, int n) {
  __shared__ int sm[256];
  const int i = blockIdx.x * 256 + threadIdx.x;
  const int v = (i < n) ? deg[i] : 0;
  sm[threadIdx.x] = v;
  __syncthreads();
  for (int off = 1; off < 256; off <<= 1) {
    int t = (threadIdx.x >= off) ? sm[threadIdx.x - off] : 0;
    __syncthreads();
    sm[threadIdx.x] += t;
    __syncthreads();
  }
  if (i < n) excl[i] = sm[threadIdx.x] - v;
  if (threadIdx.x == 255) bsum[blockIdx.x] = sm[255];
}

__global__ void scanB_kernel(const int* __restrict__ bsum, int* __restrict__ boff, int nb) {
  __shared__ int sm[256];
  const int v = (threadIdx.x < nb) ? bsum[threadIdx.x] : 0;
  sm[threadIdx.x] = v;
  __syncthreads();
  for (int off = 1; off < 256; off <<= 1) {
    int t = (threadIdx.x >= off) ? sm[threadIdx.x - off] : 0;
    __syncthreads();
    sm[threadIdx.x] += t;
    __syncthreads();
  }
  if (threadIdx.x < nb) boff[threadIdx.x] = sm[threadIdx.x] - v;
}

__global__ void scanC_kernel(const int* __restrict__ deg, const int* __restrict__ excl,
                             const int* __restrict__ boff, int* __restrict__ rowptr,
                             float* __restrict__ invc, int n, int E) {
  const int i = blockIdx.x * 256 + threadIdx.x;
  if (i < n) {
    rowptr[i] = excl[i] + boff[blockIdx.x];
    invc[i] = 1.0f / (float)(deg[i] + 1);
  }
  if (i == 0) rowptr[n] = E;
}

__global__ void fill_kernel(const int* __restrict__ srcv, const int* __restrict__ dstv,
                            const int* __restrict__ rowptr, const int* __restrict__ eoff,
                            int* __restrict__ colv, int E) {
  int i = blockIdx.x * 256 + threadIdx.x;
  if (i < E) colv[rowptr[dstv[i]] + eoff[i]] = srcv[i];
}

// ---------------------------------------------------------------------------
// 128-d aggregation, quarter-wave per node, 8 loads in flight / 4 acc streams.
// ---------------------------------------------------------------------------
__global__ __launch_bounds__(256) void agg128_kernel(
    const ushort* __restrict__ T, const int* __restrict__ rowptr,
    const int* __restrict__ colv, const float* __restrict__ invc,
    ushort* __restrict__ sout, int n) {
  const int node = blockIdx.x * 16 + (threadIdx.x >> 4);
  if (node >= n) return;
  const int q = threadIdx.x & 15;
  const u32x4* Tv = (const u32x4*)T;
  float a[8] = {}, b[8] = {}, c[8] = {}, d[8] = {};
  auto addu = [](float* acc, u32x4 u) {
    const uint32_t ww[4] = {u.x, u.y, u.z, u.w};
#pragma unroll
    for (int k = 0; k < 4; ++k) {
      union { uint32_t u; float f; } lo, hi;
      lo.u = ww[k] << 16;
      hi.u = ww[k] & 0xffff0000u;
      acc[2 * k] += lo.f;
      acc[2 * k + 1] += hi.f;
    }
  };
  addu(a, Tv[(size_t)node * 16 + q]);
  const int s = rowptr[node];
  const int e = rowptr[node + 1];
  int i = s;
  for (; i + 7 < e; i += 8) {
    u32x4 u[8];
#pragma unroll
    for (int t = 0; t < 8; ++t) u[t] = Tv[(size_t)colv[i + t] * 16 + q];
    addu(a, u[0]);
    addu(b, u[1]);
    addu(c, u[2]);
    addu(d, u[3]);
    addu(a, u[4]);
    addu(b, u[5]);
    addu(c, u[6]);
    addu(d, u[7]);
  }
  for (; i + 3 < e; i += 4) {
    u32x4 u[4];
#pragma unroll
    for (int t = 0; t < 4; ++t) u[t] = Tv[(size_t)colv[i + t] * 16 + q];
    addu(a, u[0]);
    addu(b, u[1]);
    addu(c, u[2]);
    addu(d, u[3]);
  }
  for (; i < e; ++i) addu(a, Tv[(size_t)colv[i] * 16 + q]);
  const float ic = invc[node];
  u32x4 o;
#pragma unroll
  for (int k = 0; k < 4; ++k) {
    const float r0 = (a[2 * k] + b[2 * k] + c[2 * k] + d[2 * k]) * ic;
    const float r1 = (a[2 * k + 1] + b[2 * k + 1] + c[2 * k + 1] + d[2 * k + 1]) * ic;
    o[k] = (uint32_t)f2bf(r0) | ((uint32_t)f2bf(r1) << 16);
  }
  ((u32x4*)sout)[(size_t)node * 16 + q] = o;
}

__global__ void beta_kernel(const float* __restrict__ beta, float* __restrict__ betas) {
  if (threadIdx.x == 0) {
    float mx = beta[0];
    for (int i = 1; i < NLAYER + 1; ++i) mx = fmaxf(mx, beta[i]);
    float e[NLAYER + 1];
    float s = 0.f;
    for (int i = 0; i < NLAYER + 1; ++i) {
      e[i] = expf(beta[i] - mx);
      s += e[i];
    }
    const float inv = 1.f / s;
    for (int i = 0; i < NLAYER + 1; ++i) betas[i] = e[i] * inv;
  }
}

// W [L][K][N] f32 -> Wt [L][N][K] bf16 via 32x32 LDS tile
__global__ void wconv_t(const float* __restrict__ W, ushort* __restrict__ Wt,
                        int K, int Nn) {
  __shared__ float t[32][33];
  const size_t mat = (size_t)blockIdx.z * K * Nn;
  const int kk0 = blockIdx.x * 32;
  const int nn0 = blockIdx.y * 32;
  const int tx = threadIdx.x & 31;
  const int ty = threadIdx.x >> 5;  // 0..7
#pragma unroll
  for (int i = 0; i < 4; ++i)
    t[ty * 4 + i][tx] = W[mat + (size_t)(kk0 + ty * 4 + i) * Nn + nn0 + tx];
  __syncthreads();
#pragma unroll
  for (int i = 0; i < 4; ++i)
    Wt[mat + (size_t)(nn0 + ty * 4 + i) * K + kk0 + tx] = f2bf(t[tx][ty * 4 + i]);
}

// Win GEMM (z0): A f32 [M x 128] (cast to bf16 during staging),
// B bf16 [256 x 128], C bf16 [M x 256]. Tile 128x256, 8 waves, BK=64.
__global__ __launch_bounds__(512, 4) void gemm_win(
    const float* __restrict__ A, const ushort* __restrict__ B,
    const float* __restrict__ bias, ushort* __restrict__ C, int M) {
  __shared__ ushort lA[128 * 64];
  __shared__ ushort lB[256 * 64];
  const int tid = threadIdx.x;
  const int m0 = blockIdx.x * 128;
  const int lane = tid & 63;
  const int w = tid >> 6;
  const int wm = (w >> 2) * 64;
  const int wn = (w & 3) * 64;
  const int rr = tid >> 3;
  const int cc = tid & 7;
  const int ccs = cc ^ (rr & 7);
  f32x4 acc[4][4] = {};
  const int K = 128;

#pragma unroll
  for (int s = 0; s < 2; ++s) {
    const int k0 = s * 64;
#pragma unroll
    for (int p = 0; p < 2; ++p) {
      const int row = p * 64 + rr;
      const int gm = m0 + row;
      f32x4 va = {0.f, 0.f, 0.f, 0.f}, vb = {0.f, 0.f, 0.f, 0.f};
      if (gm < M) {
        const float* ga = A + (size_t)gm * K + k0 + cc * 8;
        va = *(const f32x4*)ga;
        vb = *(const f32x4*)(ga + 4);
      }
      bf16x8 hv;
#pragma unroll
      for (int e = 0; e < 4; ++e) {
        hv[e] = (short)f2bf(va[e]);
        hv[e + 4] = (short)f2bf(vb[e]);
      }
      const uint32_t off = (uint32_t)((row * 128 + cc * 16) ^ ((row & 7) << 4));
      *(bf16x8*)((char*)lA + off) = hv;
    }
#pragma unroll
    for (int p = 0; p < 4; ++p) {
      const int row = p * 64 + rr;
      gll16(B + (size_t)row * K + k0 + ccs * 8,
            lB + (size_t)(p * 64 + w * 8) * 64);
    }
    __syncthreads();
#pragma unroll
    for (int kk = 0; kk < 2; ++kk) {
      bf16x8 ah[4];
#pragma unroll
      for (int i = 0; i < 4; ++i) {
        const int arow = wm + i * 16 + (lane & 15);
        const uint32_t ao =
            (uint32_t)((arow * 128 + kk * 64 + ((lane >> 4) * 16)) ^ ((arow & 7) << 4));
        ah[i] = *(const bf16x8*)((const char*)lA + ao);
      }
#pragma unroll
      for (int j = 0; j < 4; ++j) {
        const int brow = wn + j * 16 + (lane & 15);
        const uint32_t bo =
            (uint32_t)((brow * 128 + kk * 64 + ((lane >> 4) * 16)) ^ ((brow & 7) << 4));
        const bf16x8 bv = *(const bf16x8*)((const char*)lB + bo);
#pragma unroll
        for (int i = 0; i < 4; ++i)
          acc[i][j] = __builtin_amdgcn_mfma_f32_16x16x32_bf16(ah[i], bv, acc[i][j], 0, 0, 0);
      }
    }
    __syncthreads();
  }
  float bi[4];
#pragma unroll
  for (int j = 0; j < 4; ++j) bi[j] = bias[wn + j * 16 + (lane & 15)];
#pragma unroll
  for (int i = 0; i < 4; ++i) {
    const int gm0 = m0 + wm + i * 16 + ((lane >> 4) << 2);
#pragma unroll
    for (int r = 0; r < 4; ++r) {
      const int gm = gm0 + r;
      if (gm < M) {
        const size_t base = (size_t)gm * 256 + wn + (lane & 15);
#pragma unroll
        for (int j = 0; j < 4; ++j)
          C[base + j * 16] = f2bf(acc[i][j][r] + bi[j]);
      }
    }
  }
}

// ---------------------------------------------------------------------------
extern "C" void kernel_launch(void* const* d_in, const int* in_sizes, int n_in,
                              void* d_out, int out_size, void* d_ws, size_t ws_size,
                              hipStream_t stream) {
  const float* x = (const float*)d_in[0];
  const int* eidx = (const int*)d_in[1];
  const float* Win = (const float*)d_in[2];
  const float* bin_ = (const float*)d_in[3];
  const float* W1 = (const float*)d_in[4];
  const float* b1 = (const float*)d_in[5];
  const float* W2 = (const float*)d_in[6];
  const float* b2 = (const float*)d_in[7];
  const float* U1 = (const float*)d_in[8];
  const float* c1 = (const float*)d_in[9];
  const float* U2 = (const float*)d_in[10];
  const float* c2 = (const float*)d_in[11];
  const float* ln_g = (const float*)d_in[12];
  const float* ln_b = (const float*)d_in[13];
  const float* beta = (const float*)d_in[14];
  float* outp = (float*)d_out;

  const int Nn = in_sizes[0] / 128;  // 50000
  const int E = in_sizes[1] / 2;     // 800000
  const int* srcv = eidx;
  const int* dstv = eidx + E;

  char* p = (char*)d_ws;
  auto alloc = [&](size_t bytes) {
    char* r = p;
    p += (bytes + 255) & ~(size_t)255;
    return r;
  };
  ushort* hbuf = (ushort*)alloc((size_t)Nn * HIDC * 2);  // h bf16
  ushort* TSO = (ushort*)alloc((size_t)Nn * HIDC * 2);   // T | s, later O
  ushort* WinT = (ushort*)alloc(128 * 256 * 2);
  ushort* W1T = (ushort*)alloc((size_t)NLAYER * 256 * 128 * 2);
  ushort* W2T = (ushort*)alloc((size_t)NLAYER * 128 * 256 * 2);
  ushort* U1T = (ushort*)alloc((size_t)NLAYER * 256 * 256 * 2);
  ushort* U2T = (ushort*)alloc((size_t)NLAYER * 256 * 256 * 2);
  int* deg = (int*)alloc((size_t)Nn * 4);
  int* rowptr = (int*)alloc((size_t)(Nn + 1) * 4);
  float* invc = (float*)alloc((size_t)Nn * 4);
  int* colv = (int*)alloc((size_t)E * 4);
  int* eoff = (int*)alloc((size_t)E * 4);
  int* excl = (int*)alloc((size_t)Nn * 4);
  int* bsum = (int*)alloc(256 * 4);
  int* boff = (int*)alloc(256 * 4);
  float* betas = (float*)alloc(64);

  // z-history slots: as many as fit (G in [2, 11])
  const size_t ZS = (size_t)Nn * HIDC;
  const size_t slotB = ZS * 2;
  const size_t used = (size_t)(p - (char*)d_ws);
  int G = 2;
  if (ws_size > used + 4096) {
    size_t fit = (ws_size - used - 4096) / (slotB + 256);
    G = (int)(fit < 2 ? 2 : (fit > NLAYER + 1 ? NLAYER + 1 : fit));
  }
  ushort* zbase = (ushort*)alloc((size_t)G * slotB);

  ushort* T128 = TSO;
  ushort* s128 = TSO + (size_t)Nn * MSGC;
  ushort* Obuf = TSO;  // reuses T|s after both consumed

  const int nscan = (Nn + 255) / 256;
  const int mb128 = (Nn + 127) / 128;
  const int mb64 = (Nn + 63) / 64;
  const int nagg = (Nn + 15) / 16;
  const int total16 = (Nn * HIDC) / 16;
  const int foldgrid = 2048;

  hipMemsetAsync(deg, 0, (size_t)Nn * 4, stream);
  count_kernel<<<(E + 255) / 256, 256, 0, stream>>>(dstv, deg, eoff, E);
  scanA_kernel<<<nscan, 256, 0, stream>>>(deg, excl, bsum, Nn);
  scanB_kernel<<<1, 256, 0, stream>>>(bsum, boff, nscan);
  scanC_kernel<<<nscan, 256, 0, stream>>>(deg, excl, boff, rowptr, invc, Nn, E);
  fill_kernel<<<(E + 255) / 256, 256, 0, stream>>>(srcv, dstv, rowptr, eoff, colv, E);
  beta_kernel<<<1, 64, 0, stream>>>(beta, betas);
  wconv_t<<<dim3(4, 8, 1), 256, 0, stream>>>(Win, WinT, 128, 256);
  wconv_t<<<dim3(8, 4, NLAYER), 256, 0, stream>>>(W1, W1T, 256, 128);
  wconv_t<<<dim3(4, 8, NLAYER), 256, 0, stream>>>(W2, W2T, 128, 256);
  wconv_t<<<dim3(8, 8, NLAYER), 256, 0, stream>>>(U1, U1T, 256, 256);
  wconv_t<<<dim3(8, 8, NLAYER), 256, 0, stream>>>(U2, U2T, 256, 256);

  // fold bookkeeping
  int pend = 0, l0 = 0;
  bool first = true;
  auto flush = [&]() {
    if (pend > 0) {
      if (first)
        fold_kernel<1><<<foldgrid, 256, 0, stream>>>(zbase, ZS, betas, l0, pend, outp,
                                                     total16);
      else
        fold_kernel<0><<<foldgrid, 256, 0, stream>>>(zbase, ZS, betas, l0, pend, outp,
                                                     total16);
      first = false;
      l0 += pend;
      pend = 0;
    }
  };

  // z0 = x @ Win + bin -> slot 0 (xcast fused into staging)
  ushort* zcur = zbase;
  gemm_win<<<mb128, 512, 0, stream>>>(x, WinT, bin_, zcur, Nn);
  pend = 1;

  for (int l = 0; l < NLAYER; ++l) {
    // T = bf16(relu(z @ W1 + b1))
    gemm_w1_64<<<mb64, 256, 0, stream>>>(zcur, W1T + (size_t)l * 256 * 128,
                                         b1 + l * 128, T128, Nn);
    // s = bf16(segmean(T))
    agg128_kernel<<<nagg, 256, 0, stream>>>(T128, rowptr, colv, invc, s128, Nn);
    // h = bf16(z + s @ W2 + b2)
    gemm_big64<0, 1, 0><<<mb64, 256, 0, stream>>>(s128, W2T + (size_t)l * 128 * 256,
                                                  b2 + l * 256, zcur, hbuf, nullptr,
                                                  nullptr, Nn, 128);
    // O = bf16(relu(h @ U1 + c1))
    gemm_big64<1, 0, 0><<<mb64, 256, 0, stream>>>(hbuf, U1T + (size_t)l * 256 * 256,
                                                  c1 + l * 256, nullptr, Obuf, nullptr,
                                                  nullptr, Nn, 256);
    // fold if all slots full
    if (pend == G) flush();
    // z' = bf16(LN(O @ U2 + c2)*g + b)
    ushort* znext = zbase + (size_t)pend * ZS;
    gemm_big64<0, 0, 1><<<mb64, 256, 0, stream>>>(Obuf, U2T + (size_t)l * 256 * 256,
                                                  c2 + l * 256, nullptr, znext,
                                                  ln_g + l * 256, ln_b + l * 256, Nn, 256);
    zcur = znext;
    pend++;
  }
  flush();
}